// Round 5
// baseline (919.483 us; speedup 1.0000x reference)
//
#include <hip/hip_runtime.h>
#include <hip/hip_bf16.h>

#define NN 30000
#define NE 480000

typedef __attribute__((ext_vector_type(8))) short short8;
typedef __attribute__((ext_vector_type(4))) float floatx4;

__device__ __forceinline__ short2 split_bf16(float f) {
    __hip_bfloat16 h = __float2bfloat16(f);          // RTNE high part
    float r = f - __bfloat162float(h);               // residual, |r| <= 2^-9 |f|
    __hip_bfloat16 l = __float2bfloat16(r);
    short2 out;
    out.x = *reinterpret_cast<short*>(&h);
    out.y = *reinterpret_cast<short*>(&l);
    return out;
}

// ---- presplit: fp32 W[K][N] -> transposed bf16 hi/lo [N][K] ----
__global__ void presplit_kernel(const float* __restrict__ W, int K, int N,
                                short* __restrict__ hi, short* __restrict__ lo)
{
    int i = blockIdx.x * 256 + threadIdx.x;
    if (i >= K * N) return;
    int k = i / N, n = i - k * N;
    short2 s = split_bf16(W[i]);
    hi[(size_t)n * K + k] = s.x;
    lo[(size_t)n * K + k] = s.y;
}

// ---- GEMM: C[M,N] = A[M,K] @ W[K,N] + bias (+res). A fp32 (split in-kernel),
// B pre-split transposed bf16 [N][K]. One 16x16 tile per wave. K % 32 == 0.
template<int K, int N>
__launch_bounds__(256)
__global__ void gemm_mfma(const float* __restrict__ A, const short* __restrict__ Bh,
                          const short* __restrict__ Bl, const float* __restrict__ bias,
                          const float* __restrict__ res, float* __restrict__ C, int total_waves)
{
    int wave = ((blockIdx.x * 256) + threadIdx.x) >> 6;
    if (wave >= total_waves) return;
    constexpr int NT = (N + 15) / 16;
    const int mt = wave / NT, nt = wave % NT;
    const int lane = threadIdx.x & 63;
    const int l15 = lane & 15, quad = lane >> 4;
    const int row = mt * 16 + l15;
    const int col = nt * 16 + l15;
    const bool cok = (col < N);
    floatx4 acc = {0.f, 0.f, 0.f, 0.f};
#pragma unroll
    for (int k0 = 0; k0 < K; k0 += 32) {
        const int kb = k0 + quad * 8;
        short8 ah, al, bh, bl;
        const float* ap = A + (size_t)row * K + kb;
        floatx4 a0 = *(const floatx4*)ap;
        floatx4 a1 = *(const floatx4*)(ap + 4);
#pragma unroll
        for (int j = 0; j < 4; j++) {
            short2 s0 = split_bf16(a0[j]); ah[j] = s0.x; al[j] = s0.y;
            short2 s1 = split_bf16(a1[j]); ah[j + 4] = s1.x; al[j + 4] = s1.y;
        }
        if (cok) {
            bh = *(const short8*)(Bh + (size_t)col * K + kb);
            bl = *(const short8*)(Bl + (size_t)col * K + kb);
        } else {
#pragma unroll
            for (int j = 0; j < 8; j++) { bh[j] = 0; bl[j] = 0; }
        }
        acc = __builtin_amdgcn_mfma_f32_16x16x32_bf16(ah, bh, acc, 0, 0, 0);
        acc = __builtin_amdgcn_mfma_f32_16x16x32_bf16(al, bh, acc, 0, 0, 0);
        acc = __builtin_amdgcn_mfma_f32_16x16x32_bf16(ah, bl, acc, 0, 0, 0);
    }
    if (cok) {
        float bv = bias[col];
#pragma unroll
        for (int r = 0; r < 4; r++) {
            int ro = mt * 16 + quad * 4 + r;   // C/D: col=lane&15, row=quad*4+reg
            float v = acc[r] + bv;
            if (res) v += res[(size_t)ro * N + col];
            C[(size_t)ro * N + col] = v;
        }
    }
}

// ---- relu(LayerNorm(x)*g+b), one wave per node ----
template<int H>
__launch_bounds__(256)
__global__ void relu_ln_kernel(const float* __restrict__ X, const float* __restrict__ g,
                               const float* __restrict__ b, float* __restrict__ Y)
{
    constexpr int V = H / 64;
    int node = (blockIdx.x * 256 + threadIdx.x) >> 6;
    int lane = threadIdx.x & 63;
    if (node >= NN) return;
    const float* xr = X + (size_t)node * H + lane * V;
    float v[V];
#pragma unroll
    for (int i = 0; i < V; i++) v[i] = xr[i];
    float sm = 0.f;
#pragma unroll
    for (int i = 0; i < V; i++) sm += v[i];
#pragma unroll
    for (int m = 32; m; m >>= 1) sm += __shfl_xor(sm, m, 64);
    float mean = sm * (1.0f / H);
    float vs = 0.f;
#pragma unroll
    for (int i = 0; i < V; i++) { float d = v[i] - mean; vs += d * d; }
#pragma unroll
    for (int m = 32; m; m >>= 1) vs += __shfl_xor(vs, m, 64);
    float rs = rsqrtf(vs * (1.0f / H) + 1e-5f);
    float* yr = Y + (size_t)node * H + lane * V;
#pragma unroll
    for (int i = 0; i < V; i++) {
        int c = lane * V + i;
        float y = (v[i] - mean) * rs * g[c] + b[c];
        yr[i] = fmaxf(y, 0.f);
    }
}

// ---- zero fill ----
__global__ void zero_kernel(int* __restrict__ p, int n)
{
    int i = blockIdx.x * 256 + threadIdx.x;
    if (i < n) p[i] = 0;
}

// ---- CSR build: histogram of dst ----
__global__ void hist_kernel(const int* __restrict__ dst, int* __restrict__ count)
{
    int e = blockIdx.x * 256 + threadIdx.x;
    if (e < NE) atomicAdd(count + dst[e], 1);
}

// ---- CSR build: single-block exclusive scan of count[NN] -> rowptr[NN+1] ----
__launch_bounds__(1024)
__global__ void scan_kernel(const int* __restrict__ count, int* __restrict__ rowptr)
{
    __shared__ int part[1024];
    const int t = threadIdx.x;
    const int CH = (NN + 1023) / 1024;          // 30
    const int base = t * CH;
    int sum = 0;
    for (int j = 0; j < CH; j++) {
        int idx = base + j;
        if (idx < NN) sum += count[idx];
    }
    part[t] = sum;
    __syncthreads();
    for (int d = 1; d < 1024; d <<= 1) {
        int v = (t >= d) ? part[t - d] : 0;
        __syncthreads();
        part[t] += v;
        __syncthreads();
    }
    int off = (t == 0) ? 0 : part[t - 1];
    for (int j = 0; j < CH; j++) {
        int idx = base + j;
        if (idx < NN) { rowptr[idx] = off; off += count[idx]; }
    }
    if (t == 1023) rowptr[NN] = part[1023];
}

// ---- CSR build: scatter src + bf16 edge attrs into CSR order (no eidx indirection) ----
__global__ void scatter_kernel(const int* __restrict__ src, const int* __restrict__ dst,
                               const float* __restrict__ edge_attr,
                               const int* __restrict__ rowptr, int* __restrict__ cursor,
                               int* __restrict__ src_csr, unsigned* __restrict__ attr_csr)
{
    int e = blockIdx.x * 256 + threadIdx.x;
    if (e >= NE) return;
    int d = dst[e];
    int pos = rowptr[d] + atomicAdd(cursor + d, 1);
    src_csr[pos] = src[e];
    const float4* ap = (const float4*)(edge_attr + (size_t)e * 16);
    unsigned* op = attr_csr + (size_t)pos * 8;
#pragma unroll
    for (int q = 0; q < 4; q++) {
        float4 v = ap[q];
        __hip_bfloat16 b0 = __float2bfloat16(v.x), b1 = __float2bfloat16(v.y);
        __hip_bfloat16 b2 = __float2bfloat16(v.z), b3 = __float2bfloat16(v.w);
        op[2 * q]     = (unsigned)*(unsigned short*)&b0 | ((unsigned)*(unsigned short*)&b1 << 16);
        op[2 * q + 1] = (unsigned)*(unsigned short*)&b2 | ((unsigned)*(unsigned short*)&b3 << 16);
    }
}

// ---- fused aggregation: on-the-fly edge encoding + online softmax, one wave per node ----
__device__ __forceinline__ void edge_ea(uint4 p0, uint4 p1, const float* W0, const float* W1,
                                        float2 eb, float& o0, float& o1)
{
    unsigned u[8] = {p0.x, p0.y, p0.z, p0.w, p1.x, p1.y, p1.z, p1.w};
    float a[16];
#pragma unroll
    for (int i = 0; i < 8; i++) {
        a[2 * i]     = __uint_as_float(u[i] << 16);
        a[2 * i + 1] = __uint_as_float(u[i] & 0xffff0000u);
    }
    float s0 = eb.x, s1 = eb.y;
#pragma unroll
    for (int k = 0; k < 16; k++) { s0 = fmaf(a[k], W0[k], s0); s1 = fmaf(a[k], W1[k], s1); }
    o0 = s0; o1 = s1;
}

__device__ __forceinline__ void online_upd(float hv, float av, float tt,
                                           float& m, float& s, float& n)
{
    float g = fmaxf(hv + av, 0.f) + 1e-7f;     // msg
    float l = g * tt;                          // logit
    float nm = fmaxf(m, l);
    float c = __expf(m - nm);
    float d = __expf(l - nm);
    s = s * c + d;
    n = n * c + g * d;
    m = nm;
}

__launch_bounds__(256)
__global__ void agg_kernel(const float* __restrict__ hin,
                           const unsigned* __restrict__ attr_csr,
                           const int* __restrict__ src_csr,
                           const int* __restrict__ rowptr,
                           const float* __restrict__ ew, const float* __restrict__ ebias,
                           const float* __restrict__ tptr, int layer,
                           float* __restrict__ zout)
{
    int node = (blockIdx.x * 256 + threadIdx.x) >> 6;
    if (node >= NN) return;
    const int lane = threadIdx.x & 63;
    // preload this lane's 2 columns of edge_enc_w + bias into registers
    float W0[16], W1[16];
    const float2* ew2 = (const float2*)ew;
#pragma unroll
    for (int k = 0; k < 16; k++) { float2 wv = ew2[k * 64 + lane]; W0[k] = wv.x; W1[k] = wv.y; }
    float2 eb2 = ((const float2*)ebias)[lane];
    const float tt = tptr[layer];
    const float2* h2 = (const float2*)hin;
    int j = rowptr[node];
    const int end = rowptr[node + 1];
    float m0 = -1e30f, m1 = -1e30f, s0 = 0.f, s1 = 0.f, n0 = 0.f, n1 = 0.f;
    for (; j + 2 <= end; j += 2) {
        int sa = src_csr[j], sb = src_csr[j + 1];
        uint4 pa0 = *(const uint4*)(attr_csr + (size_t)j * 8);
        uint4 pa1 = *(const uint4*)(attr_csr + (size_t)j * 8 + 4);
        uint4 pb0 = *(const uint4*)(attr_csr + (size_t)(j + 1) * 8);
        uint4 pb1 = *(const uint4*)(attr_csr + (size_t)(j + 1) * 8 + 4);
        float2 ha = h2[(size_t)sa * 64 + lane];
        float2 hb = h2[(size_t)sb * 64 + lane];
        float ea0, ea1, eb0, eb1;
        edge_ea(pa0, pa1, W0, W1, eb2, ea0, ea1);
        edge_ea(pb0, pb1, W0, W1, eb2, eb0, eb1);
        online_upd(ha.x, ea0, tt, m0, s0, n0);
        online_upd(ha.y, ea1, tt, m1, s1, n1);
        online_upd(hb.x, eb0, tt, m0, s0, n0);
        online_upd(hb.y, eb1, tt, m1, s1, n1);
    }
    if (j < end) {
        int sa = src_csr[j];
        uint4 pa0 = *(const uint4*)(attr_csr + (size_t)j * 8);
        uint4 pa1 = *(const uint4*)(attr_csr + (size_t)j * 8 + 4);
        float2 ha = h2[(size_t)sa * 64 + lane];
        float ea0, ea1;
        edge_ea(pa0, pa1, W0, W1, eb2, ea0, ea1);
        online_upd(ha.x, ea0, tt, m0, s0, n0);
        online_upd(ha.y, ea1, tt, m1, s1, n1);
    }
    float2 res = h2[(size_t)node * 64 + lane];
    float2 o;
    o.x = n0 / (s0 + 1e-16f) + res.x;
    o.y = n1 / (s1 + 1e-16f) + res.y;
    ((float2*)zout)[(size_t)node * 64 + lane] = o;
}

extern "C" void kernel_launch(void* const* d_in, const int* in_sizes, int n_in,
                              void* d_out, int out_size, void* d_ws, size_t ws_size,
                              hipStream_t stream)
{
    const float* x         = (const float*)d_in[0];
    const float* edge_attr = (const float*)d_in[1];
    const float* nw        = (const float*)d_in[2];
    const float* nb        = (const float*)d_in[3];
    const float* ew        = (const float*)d_in[4];
    const float* eb        = (const float*)d_in[5];
    const float* m1w       = (const float*)d_in[6];
    const float* m1b       = (const float*)d_in[7];
    const float* lng       = (const float*)d_in[8];
    const float* lnb       = (const float*)d_in[9];
    const float* m2w       = (const float*)d_in[10];
    const float* m2b       = (const float*)d_in[11];
    const float* tpr       = (const float*)d_in[12];
    const float* ng        = (const float*)d_in[13];
    const float* nbb       = (const float*)d_in[14];
    const float* lw        = (const float*)d_in[15];
    const float* lb        = (const float*)d_in[16];
    const int* ei  = (const int*)d_in[17];
    const int* src = ei;
    const int* dst = ei + NE;

    // ---- workspace carve (~112 MB) ----
    char* w = (char*)d_ws;
    unsigned* attr_csr = (unsigned*)w; w += (size_t)NE * 32;            // 15.36 MB
    float* hA   = (float*)w; w += (size_t)NN * 128 * 4;
    float* hB   = (float*)w; w += (size_t)NN * 128 * 4;
    float* hin  = (float*)w; w += (size_t)NN * 128 * 4;
    float* zbuf = (float*)w; w += (size_t)NN * 128 * 4;
    float* z1   = (float*)w; w += (size_t)NN * 256 * 4;
    int* src_csr = (int*)w;  w += (size_t)NE * 4;
    // pre-split transposed weights (bf16 hi/lo)
    short* nw_h = (short*)w;  w += (size_t)64 * 128 * 2;
    short* nw_l = (short*)w;  w += (size_t)64 * 128 * 2;
    short* m1_h = (short*)w;  w += (size_t)3 * 128 * 256 * 2;
    short* m1_l = (short*)w;  w += (size_t)3 * 128 * 256 * 2;
    short* m2_h = (short*)w;  w += (size_t)3 * 256 * 128 * 2;
    short* m2_l = (short*)w;  w += (size_t)3 * 256 * 128 * 2;
    short* lw_h = (short*)w;  w += (size_t)128 * 16 * 2;
    short* lw_l = (short*)w;  w += (size_t)128 * 16 * 2;
    int* count  = (int*)w;   w += (size_t)NN * 4;
    int* cursor = (int*)w;   w += (size_t)NN * 4;
    int* rowptr = (int*)w;   w += (size_t)(NN + 1) * 4;

    // ---- CSR build (reused by all 3 layers) ----
    zero_kernel<<<(2 * NN + 255) / 256, 256, 0, stream>>>(count, 2 * NN);  // count+cursor contiguous
    hist_kernel<<<(NE + 255) / 256, 256, 0, stream>>>(dst, count);
    scan_kernel<<<1, 1024, 0, stream>>>(count, rowptr);
    scatter_kernel<<<(NE + 255) / 256, 256, 0, stream>>>(src, dst, edge_attr, rowptr, cursor,
                                                         src_csr, attr_csr);

    // ---- weight pre-split (transposed bf16 hi/lo) ----
    presplit_kernel<<<(64 * 128 + 255) / 256, 256, 0, stream>>>(nw, 64, 128, nw_h, nw_l);
    for (int l = 0; l < 3; l++) {
        presplit_kernel<<<(128 * 256 + 255) / 256, 256, 0, stream>>>(
            m1w + (size_t)l * 128 * 256, 128, 256, m1_h + (size_t)l * 256 * 128, m1_l + (size_t)l * 256 * 128);
        presplit_kernel<<<(256 * 128 + 255) / 256, 256, 0, stream>>>(
            m2w + (size_t)l * 256 * 128, 256, 128, m2_h + (size_t)l * 128 * 256, m2_l + (size_t)l * 128 * 256);
    }
    presplit_kernel<<<(128 * 10 + 255) / 256, 256, 0, stream>>>(lw, 128, 10, lw_h, lw_l);

    // ---- node encoder ----
    gemm_mfma<64, 128><<<(NN / 16) * 8 / 4, 256, 0, stream>>>(x, nw_h, nw_l, nb, nullptr, hA, (NN / 16) * 8);

    float* h = hA; float* hn = hB;
    for (int layer = 0; layer < 3; ++layer) {
        const float* hi;
        if (layer == 0) {
            hi = h;
        } else {
            relu_ln_kernel<128><<<NN / 4, 256, 0, stream>>>(h, ng + layer * 128, nbb + layer * 128, hin);
            hi = hin;
        }
        agg_kernel<<<(NN + 3) / 4, 256, 0, stream>>>(hi, attr_csr, src_csr, rowptr, ew, eb, tpr, layer, zbuf);
        gemm_mfma<128, 256><<<(NN / 16) * 16 / 4, 256, 0, stream>>>(
            zbuf, m1_h + (size_t)layer * 256 * 128, m1_l + (size_t)layer * 256 * 128,
            m1b + layer * 256, nullptr, z1, (NN / 16) * 16);
        relu_ln_kernel<256><<<NN / 4, 256, 0, stream>>>(z1, lng + layer * 256, lnb + layer * 256, z1);
        gemm_mfma<256, 128><<<(NN / 16) * 8 / 4, 256, 0, stream>>>(
            z1, m2_h + (size_t)layer * 128 * 256, m2_l + (size_t)layer * 128 * 256,
            m2b + layer * 128, (layer > 0) ? h : nullptr, hn, (NN / 16) * 8);
        float* tmp = h; h = hn; hn = tmp;
    }
    // final norm (layer-0 params) + classifier
    relu_ln_kernel<128><<<NN / 4, 256, 0, stream>>>(h, ng, nbb, hin);
    gemm_mfma<128, 10><<<(NN / 16 + 3) / 4, 256, 0, stream>>>(
        hin, lw_h, lw_l, lb, nullptr, (float*)d_out, NN / 16);
}

// Round 6
// 768.547 us; speedup vs baseline: 1.1964x; 1.1964x over previous
//
#include <hip/hip_runtime.h>
#include <hip/hip_bf16.h>

#define NN 30000
#define NE 480000

typedef __attribute__((ext_vector_type(8))) short short8;
typedef __attribute__((ext_vector_type(4))) float floatx4;

__device__ __forceinline__ short2 split_bf16(float f) {
    __hip_bfloat16 h = __float2bfloat16(f);          // RTNE high part
    float r = f - __bfloat162float(h);               // residual, |r| <= 2^-9 |f|
    __hip_bfloat16 l = __float2bfloat16(r);
    short2 out;
    out.x = *reinterpret_cast<short*>(&h);
    out.y = *reinterpret_cast<short*>(&l);
    return out;
}

// ---- presplit: fp32 W[K][N] -> transposed bf16 hi/lo [Npad][K] (rows n>=N zeroed) ----
__global__ void presplit_kernel(const float* __restrict__ W, int K, int N, int Npad,
                                short* __restrict__ hi, short* __restrict__ lo)
{
    int i = blockIdx.x * 256 + threadIdx.x;
    if (i >= K * Npad) return;
    int k = i / Npad, n = i - k * Npad;
    short2 s = (n < N) ? split_bf16(W[(size_t)k * N + n]) : short2{0, 0};
    hi[(size_t)n * K + k] = s.x;
    lo[(size_t)n * K + k] = s.y;
}

// ---- GEMM (A fp32, split in-kernel): node encoder only. One 16x16 tile/wave. ----
template<int K, int N>
__launch_bounds__(256)
__global__ void gemm_a32(const float* __restrict__ A, const short* __restrict__ Bh,
                         const short* __restrict__ Bl, const float* __restrict__ bias,
                         float* __restrict__ C, int total_waves)
{
    int wave = ((blockIdx.x * 256) + threadIdx.x) >> 6;
    if (wave >= total_waves) return;
    constexpr int NT = N / 16;
    const int mt = wave / NT, nt = wave % NT;
    const int lane = threadIdx.x & 63;
    const int l15 = lane & 15, quad = lane >> 4;
    const int row = mt * 16 + l15;
    const int col = nt * 16 + l15;
    floatx4 acc = {0.f, 0.f, 0.f, 0.f};
#pragma unroll
    for (int k0 = 0; k0 < K; k0 += 32) {
        const int kb = k0 + quad * 8;
        short8 ah, al;
        const float* ap = A + (size_t)row * K + kb;
        floatx4 a0 = *(const floatx4*)ap;
        floatx4 a1 = *(const floatx4*)(ap + 4);
#pragma unroll
        for (int j = 0; j < 4; j++) {
            short2 s0 = split_bf16(a0[j]); ah[j] = s0.x; al[j] = s0.y;
            short2 s1 = split_bf16(a1[j]); ah[j + 4] = s1.x; al[j + 4] = s1.y;
        }
        short8 bh = *(const short8*)(Bh + (size_t)col * K + kb);
        short8 bl = *(const short8*)(Bl + (size_t)col * K + kb);
        acc = __builtin_amdgcn_mfma_f32_16x16x32_bf16(ah, bh, acc, 0, 0, 0);
        acc = __builtin_amdgcn_mfma_f32_16x16x32_bf16(al, bh, acc, 0, 0, 0);
        acc = __builtin_amdgcn_mfma_f32_16x16x32_bf16(ah, bl, acc, 0, 0, 0);
    }
    float bv = bias[col];
#pragma unroll
    for (int r = 0; r < 4; r++) {
        int ro = mt * 16 + quad * 4 + r;   // C/D: col=lane&15, row=quad*4+reg
        C[(size_t)ro * N + col] = acc[r] + bv;
    }
}

// ---- GEMM (A pre-split bf16 hi/lo [M][K]): 16 x (16*NTW) tile per wave ----
// NREAL: real N (output stride & guard); NTOT: padded (B layout), multiple of 16*NTW.
template<int K, int NTOT, int NTW, int NREAL>
__launch_bounds__(256)
__global__ void gemm_s(const short* __restrict__ Ah, const short* __restrict__ Al,
                       const short* __restrict__ Bh, const short* __restrict__ Bl,
                       const float* __restrict__ bias, const float* __restrict__ res,
                       float* __restrict__ C, int total_waves)
{
    int wave = ((blockIdx.x * 256) + threadIdx.x) >> 6;
    if (wave >= total_waves) return;
    constexpr int NG = NTOT / (16 * NTW);
    const int mt = wave / NG, g = wave % NG;
    const int lane = threadIdx.x & 63;
    const int l15 = lane & 15, quad = lane >> 4;
    const int row = mt * 16 + l15;
    floatx4 acc[NTW];
#pragma unroll
    for (int t = 0; t < NTW; t++) acc[t] = {0.f, 0.f, 0.f, 0.f};
#pragma unroll
    for (int k0 = 0; k0 < K; k0 += 32) {
        const int kb = k0 + quad * 8;
        short8 ah = *(const short8*)(Ah + (size_t)row * K + kb);
        short8 al = *(const short8*)(Al + (size_t)row * K + kb);
#pragma unroll
        for (int t = 0; t < NTW; t++) {
            int col = g * NTW * 16 + t * 16 + l15;
            short8 bh = *(const short8*)(Bh + (size_t)col * K + kb);
            short8 bl = *(const short8*)(Bl + (size_t)col * K + kb);
            acc[t] = __builtin_amdgcn_mfma_f32_16x16x32_bf16(ah, bh, acc[t], 0, 0, 0);
            acc[t] = __builtin_amdgcn_mfma_f32_16x16x32_bf16(al, bh, acc[t], 0, 0, 0);
            acc[t] = __builtin_amdgcn_mfma_f32_16x16x32_bf16(ah, bl, acc[t], 0, 0, 0);
        }
    }
#pragma unroll
    for (int t = 0; t < NTW; t++) {
        int col = g * NTW * 16 + t * 16 + l15;
        if (col < NREAL) {
            float bv = bias[col];
#pragma unroll
            for (int r = 0; r < 4; r++) {
                int ro = mt * 16 + quad * 4 + r;
                float v = acc[t][r] + bv;
                if (res) v += res[(size_t)ro * NREAL + col];
                C[(size_t)ro * NREAL + col] = v;   // in-place over res is safe (same thread RAW)
            }
        }
    }
}

// ---- edge-encoder GEMM: ea_csr[NE,128]bf16 = attr_csr[NE,16]bf16 @ ew + eb ----
__launch_bounds__(256)
__global__ void gemm_ea(const unsigned* __restrict__ attr, const short* __restrict__ Bh,
                        const short* __restrict__ Bl, const float* __restrict__ bias,
                        __hip_bfloat16* __restrict__ ea, int total_waves)
{
    int wave = ((blockIdx.x * 256) + threadIdx.x) >> 6;
    if (wave >= total_waves) return;
    const int mt = wave >> 1, g = wave & 1;       // 2 groups of 64 cols
    const int lane = threadIdx.x & 63;
    const int l15 = lane & 15, quad = lane >> 4;
    const int row = mt * 16 + l15;
    short8 a;
    if (quad < 2) {
        uint4 p = *(const uint4*)(attr + (size_t)row * 8 + quad * 4);
        a = *reinterpret_cast<short8*>(&p);
    } else {
#pragma unroll
        for (int j = 0; j < 8; j++) a[j] = 0;
    }
    floatx4 acc[4];
#pragma unroll
    for (int t = 0; t < 4; t++) acc[t] = {0.f, 0.f, 0.f, 0.f};
#pragma unroll
    for (int t = 0; t < 4; t++) {
        int col = g * 64 + t * 16 + l15;
        short8 bh, bl;
        if (quad < 2) {
            bh = *(const short8*)(Bh + (size_t)col * 16 + quad * 8);
            bl = *(const short8*)(Bl + (size_t)col * 16 + quad * 8);
        } else {
#pragma unroll
            for (int j = 0; j < 8; j++) { bh[j] = 0; bl[j] = 0; }
        }
        acc[t] = __builtin_amdgcn_mfma_f32_16x16x32_bf16(a, bh, acc[t], 0, 0, 0);
        acc[t] = __builtin_amdgcn_mfma_f32_16x16x32_bf16(a, bl, acc[t], 0, 0, 0);
    }
#pragma unroll
    for (int t = 0; t < 4; t++) {
        int col = g * 64 + t * 16 + l15;
        float bv = bias[col];
#pragma unroll
        for (int r = 0; r < 4; r++) {
            int ro = mt * 16 + quad * 4 + r;
            ea[(size_t)ro * 128 + col] = __float2bfloat16(acc[t][r] + bv);
        }
    }
}

// ---- relu(LayerNorm(x)*g+b): OUT_SPLIT ? bf16 hi/lo pair : fp32 ----
template<int H, bool OUT_SPLIT>
__launch_bounds__(256)
__global__ void relu_ln_kernel(const float* __restrict__ X, const float* __restrict__ g,
                               const float* __restrict__ b, float* __restrict__ Y,
                               short* __restrict__ Yh, short* __restrict__ Yl)
{
    constexpr int V = H / 64;
    int node = (blockIdx.x * 256 + threadIdx.x) >> 6;
    int lane = threadIdx.x & 63;
    if (node >= NN) return;
    const float* xr = X + (size_t)node * H + lane * V;
    float v[V];
#pragma unroll
    for (int i = 0; i < V; i++) v[i] = xr[i];
    float sm = 0.f;
#pragma unroll
    for (int i = 0; i < V; i++) sm += v[i];
#pragma unroll
    for (int m = 32; m; m >>= 1) sm += __shfl_xor(sm, m, 64);
    float mean = sm * (1.0f / H);
    float vs = 0.f;
#pragma unroll
    for (int i = 0; i < V; i++) { float d = v[i] - mean; vs += d * d; }
#pragma unroll
    for (int m = 32; m; m >>= 1) vs += __shfl_xor(vs, m, 64);
    float rs = rsqrtf(vs * (1.0f / H) + 1e-5f);
    if constexpr (OUT_SPLIT) {
        short vh[V], vl[V];
#pragma unroll
        for (int i = 0; i < V; i++) {
            int c = lane * V + i;
            float y = fmaxf((v[i] - mean) * rs * g[c] + b[c], 0.f);
            short2 s = split_bf16(y); vh[i] = s.x; vl[i] = s.y;
        }
        *(short2*)(Yh + (size_t)node * H + lane * V) = *(short2*)vh;   // V==2 for H=128
        *(short2*)(Yl + (size_t)node * H + lane * V) = *(short2*)vl;
        if constexpr (V == 4) {
            *(short2*)(Yh + (size_t)node * H + lane * V + 2) = *(short2*)(vh + 2);
            *(short2*)(Yl + (size_t)node * H + lane * V + 2) = *(short2*)(vl + 2);
        }
    } else {
        float* yr = Y + (size_t)node * H + lane * V;
#pragma unroll
        for (int i = 0; i < V; i++) {
            int c = lane * V + i;
            yr[i] = fmaxf((v[i] - mean) * rs * g[c] + b[c], 0.f);
        }
    }
}

// ---- zero fill ----
__global__ void zero_kernel(int* __restrict__ p, int n)
{
    int i = blockIdx.x * 256 + threadIdx.x;
    if (i < n) p[i] = 0;
}

// ---- CSR build ----
__global__ void hist_kernel(const int* __restrict__ dst, int* __restrict__ count)
{
    int e = blockIdx.x * 256 + threadIdx.x;
    if (e < NE) atomicAdd(count + dst[e], 1);
}

__launch_bounds__(1024)
__global__ void scan_kernel(const int* __restrict__ count, int* __restrict__ rowptr)
{
    __shared__ int part[1024];
    const int t = threadIdx.x;
    const int CH = (NN + 1023) / 1024;          // 30
    const int base = t * CH;
    int sum = 0;
    for (int j = 0; j < CH; j++) {
        int idx = base + j;
        if (idx < NN) sum += count[idx];
    }
    part[t] = sum;
    __syncthreads();
    for (int d = 1; d < 1024; d <<= 1) {
        int v = (t >= d) ? part[t - d] : 0;
        __syncthreads();
        part[t] += v;
        __syncthreads();
    }
    int off = (t == 0) ? 0 : part[t - 1];
    for (int j = 0; j < CH; j++) {
        int idx = base + j;
        if (idx < NN) { rowptr[idx] = off; off += count[idx]; }
    }
    if (t == 1023) rowptr[NN] = part[1023];
}

__global__ void scatter_kernel(const int* __restrict__ src, const int* __restrict__ dst,
                               const float* __restrict__ edge_attr,
                               const int* __restrict__ rowptr, int* __restrict__ cursor,
                               int* __restrict__ src_csr, unsigned* __restrict__ attr_csr)
{
    int e = blockIdx.x * 256 + threadIdx.x;
    if (e >= NE) return;
    int d = dst[e];
    int pos = rowptr[d] + atomicAdd(cursor + d, 1);
    src_csr[pos] = src[e];
    const float4* ap = (const float4*)(edge_attr + (size_t)e * 16);
    unsigned* op = attr_csr + (size_t)pos * 8;
#pragma unroll
    for (int q = 0; q < 4; q++) {
        float4 v = ap[q];
        __hip_bfloat16 b0 = __float2bfloat16(v.x), b1 = __float2bfloat16(v.y);
        __hip_bfloat16 b2 = __float2bfloat16(v.z), b3 = __float2bfloat16(v.w);
        op[2 * q]     = (unsigned)*(unsigned short*)&b0 | ((unsigned)*(unsigned short*)&b1 << 16);
        op[2 * q + 1] = (unsigned)*(unsigned short*)&b2 | ((unsigned)*(unsigned short*)&b3 << 16);
    }
}

// ---- fused aggregation: streamed ea_csr + online softmax, one wave per node ----
__device__ __forceinline__ void online_upd(float hv, float av, float tt,
                                           float& m, float& s, float& n)
{
    float g = fmaxf(hv + av, 0.f) + 1e-7f;     // msg
    float l = g * tt;                          // logit
    float nm = fmaxf(m, l);
    float c = __expf(m - nm);
    float d = __expf(l - nm);
    s = s * c + d;
    n = n * c + g * d;
    m = nm;
}

__launch_bounds__(256)
__global__ void agg_kernel(const float* __restrict__ hin,
                           const unsigned* __restrict__ ea32,   // ea_csr as packed bf16x2
                           const int* __restrict__ src_csr,
                           const int* __restrict__ rowptr,
                           const float* __restrict__ tptr, int layer,
                           short* __restrict__ Zh, short* __restrict__ Zl)
{
    int node = (blockIdx.x * 256 + threadIdx.x) >> 6;
    if (node >= NN) return;
    const int lane = threadIdx.x & 63;
    const float tt = tptr[layer];
    const float2* h2 = (const float2*)hin;
    int j = rowptr[node];
    const int end = rowptr[node + 1];
    float m0 = -1e30f, m1 = -1e30f, s0 = 0.f, s1 = 0.f, n0 = 0.f, n1 = 0.f;
    for (; j + 2 <= end; j += 2) {
        int sa = src_csr[j], sb = src_csr[j + 1];
        unsigned ua = ea32[(size_t)j * 64 + lane];
        unsigned ub = ea32[(size_t)(j + 1) * 64 + lane];
        float2 ha = h2[(size_t)sa * 64 + lane];
        float2 hb = h2[(size_t)sb * 64 + lane];
        online_upd(ha.x, __uint_as_float(ua << 16), tt, m0, s0, n0);
        online_upd(ha.y, __uint_as_float(ua & 0xffff0000u), tt, m1, s1, n1);
        online_upd(hb.x, __uint_as_float(ub << 16), tt, m0, s0, n0);
        online_upd(hb.y, __uint_as_float(ub & 0xffff0000u), tt, m1, s1, n1);
    }
    if (j < end) {
        int sa = src_csr[j];
        unsigned ua = ea32[(size_t)j * 64 + lane];
        float2 ha = h2[(size_t)sa * 64 + lane];
        online_upd(ha.x, __uint_as_float(ua << 16), tt, m0, s0, n0);
        online_upd(ha.y, __uint_as_float(ua & 0xffff0000u), tt, m1, s1, n1);
    }
    float2 res = h2[(size_t)node * 64 + lane];
    float ox = n0 / (s0 + 1e-16f) + res.x;
    float oy = n1 / (s1 + 1e-16f) + res.y;
    short2 sx = split_bf16(ox), sy = split_bf16(oy);
    ((unsigned*)Zh)[(size_t)node * 64 + lane] =
        (unsigned)(unsigned short)sx.x | ((unsigned)(unsigned short)sy.x << 16);
    ((unsigned*)Zl)[(size_t)node * 64 + lane] =
        (unsigned)(unsigned short)sx.y | ((unsigned)(unsigned short)sy.y << 16);
}

extern "C" void kernel_launch(void* const* d_in, const int* in_sizes, int n_in,
                              void* d_out, int out_size, void* d_ws, size_t ws_size,
                              hipStream_t stream)
{
    const float* x         = (const float*)d_in[0];
    const float* edge_attr = (const float*)d_in[1];
    const float* nw        = (const float*)d_in[2];
    const float* nb        = (const float*)d_in[3];
    const float* ew        = (const float*)d_in[4];
    const float* eb        = (const float*)d_in[5];
    const float* m1w       = (const float*)d_in[6];
    const float* m1b       = (const float*)d_in[7];
    const float* lng       = (const float*)d_in[8];
    const float* lnb       = (const float*)d_in[9];
    const float* m2w       = (const float*)d_in[10];
    const float* m2b       = (const float*)d_in[11];
    const float* tpr       = (const float*)d_in[12];
    const float* ng        = (const float*)d_in[13];
    const float* nbb       = (const float*)d_in[14];
    const float* lw        = (const float*)d_in[15];
    const float* lb        = (const float*)d_in[16];
    const int* ei  = (const int*)d_in[17];
    const int* src = ei;
    const int* dst = ei + NE;

    // ---- workspace carve (~203 MB high-water, aliased) ----
    char* w = (char*)d_ws;
    __hip_bfloat16* ea_csr = (__hip_bfloat16*)w; w += (size_t)NE * 128 * 2;   // 122.88 MB
    // region A (15.36 MB): attr_csr  -> later z1s_h
    unsigned* attr_csr = (unsigned*)w;
    short* z1s_h = (short*)w;          w += (size_t)NE * 32;
    // region B (15.36 MB): zbuf_h+zbuf_l -> z1s_l ; final classifier split
    short* zbuf_h = (short*)w;
    short* z1s_l  = (short*)w;
    short* fin_h  = (short*)w;         w += (size_t)NN * 128 * 2;
    short* zbuf_l = (short*)w;
    short* fin_l  = (short*)w;         w += (size_t)NN * 128 * 2;
    int*   src_csr = (int*)w;          w += (size_t)NE * 4;                   // 1.92 MB
    float* h    = (float*)w;           w += (size_t)NN * 128 * 4;             // 15.36 MB
    float* z1f  = (float*)w;                                                  // 30.72 MB
    float* hin  = (float*)w;           // aliases z1f front half (disjoint lifetime)
    int*   count  = (int*)w;           // aliases z1f (dead before L0 gemm1)
    int*   cursor = (int*)w + NN;
    w += (size_t)NN * 256 * 4;
    // weight splits (transposed bf16 hi/lo)
    short* ew_h = (short*)w; w += (size_t)128 * 16 * 2;
    short* ew_l = (short*)w; w += (size_t)128 * 16 * 2;
    short* nw_h = (short*)w; w += (size_t)128 * 64 * 2;
    short* nw_l = (short*)w; w += (size_t)128 * 64 * 2;
    short* m1_h = (short*)w; w += (size_t)3 * 256 * 128 * 2;
    short* m1_l = (short*)w; w += (size_t)3 * 256 * 128 * 2;
    short* m2_h = (short*)w; w += (size_t)3 * 128 * 256 * 2;
    short* m2_l = (short*)w; w += (size_t)3 * 128 * 256 * 2;
    short* lw_h = (short*)w; w += (size_t)16 * 128 * 2;
    short* lw_l = (short*)w; w += (size_t)16 * 128 * 2;
    int* rowptr = (int*)w;   w += (size_t)(NN + 1) * 4;

    // ---- CSR build ----
    zero_kernel<<<(2 * NN + 255) / 256, 256, 0, stream>>>(count, 2 * NN);
    hist_kernel<<<(NE + 255) / 256, 256, 0, stream>>>(dst, count);
    scan_kernel<<<1, 1024, 0, stream>>>(count, rowptr);
    scatter_kernel<<<(NE + 255) / 256, 256, 0, stream>>>(src, dst, edge_attr, rowptr, cursor,
                                                         src_csr, attr_csr);

    // ---- weight pre-split ----
    presplit_kernel<<<(16 * 128 + 255) / 256, 256, 0, stream>>>(ew, 16, 128, 128, ew_h, ew_l);
    presplit_kernel<<<(64 * 128 + 255) / 256, 256, 0, stream>>>(nw, 64, 128, 128, nw_h, nw_l);
    for (int l = 0; l < 3; l++) {
        presplit_kernel<<<(128 * 256 + 255) / 256, 256, 0, stream>>>(
            m1w + (size_t)l * 128 * 256, 128, 256, 256,
            m1_h + (size_t)l * 256 * 128, m1_l + (size_t)l * 256 * 128);
        presplit_kernel<<<(256 * 128 + 255) / 256, 256, 0, stream>>>(
            m2w + (size_t)l * 256 * 128, 256, 128, 128,
            m2_h + (size_t)l * 128 * 256, m2_l + (size_t)l * 128 * 256);
    }
    presplit_kernel<<<(128 * 16 + 255) / 256, 256, 0, stream>>>(lw, 128, 10, 16, lw_h, lw_l);

    // ---- edge encoder (once, CSR-ordered) + node encoder ----
    gemm_ea<<<(NE / 16) * 2 / 4, 256, 0, stream>>>(attr_csr, ew_h, ew_l, eb, ea_csr, (NE / 16) * 2);
    gemm_a32<64, 128><<<(NN / 16) * 8 / 4, 256, 0, stream>>>(x, nw_h, nw_l, nb, h, (NN / 16) * 8);

    const unsigned* ea32 = (const unsigned*)ea_csr;
    for (int layer = 0; layer < 3; ++layer) {
        const float* hi;
        if (layer == 0) {
            hi = h;
        } else {
            relu_ln_kernel<128, false><<<NN / 4, 256, 0, stream>>>(
                h, ng + layer * 128, nbb + layer * 128, hin, nullptr, nullptr);
            hi = hin;
        }
        agg_kernel<<<(NN + 3) / 4, 256, 0, stream>>>(hi, ea32, src_csr, rowptr, tpr, layer,
                                                     zbuf_h, zbuf_l);
        gemm_s<128, 256, 4, 256><<<(NN / 16) * 4 / 4, 256, 0, stream>>>(
            zbuf_h, zbuf_l, m1_h + (size_t)layer * 256 * 128, m1_l + (size_t)layer * 256 * 128,
            m1b + layer * 256, nullptr, z1f, (NN / 16) * 4);
        relu_ln_kernel<256, true><<<NN / 4, 256, 0, stream>>>(
            z1f, lng + layer * 256, lnb + layer * 256, nullptr, z1s_h, z1s_l);
        gemm_s<256, 128, 4, 128><<<((NN / 16) * 2 + 3) / 4, 256, 0, stream>>>(
            z1s_h, z1s_l, m2_h + (size_t)layer * 128 * 256, m2_l + (size_t)layer * 128 * 256,
            m2b + layer * 128, (layer > 0) ? h : nullptr, h, (NN / 16) * 2);
    }
    // final norm (layer-0 params) + classifier
    relu_ln_kernel<128, true><<<NN / 4, 256, 0, stream>>>(h, ng, nbb, nullptr, fin_h, fin_l);
    gemm_s<128, 16, 1, 10><<<((NN / 16) + 3) / 4, 256, 0, stream>>>(
        fin_h, fin_l, lw_h, lw_l, lb, nullptr, (float*)d_out, NN / 16);
}

// Round 7
// 685.938 us; speedup vs baseline: 1.3405x; 1.1204x over previous
//
#include <hip/hip_runtime.h>
#include <hip/hip_bf16.h>

#define NN 30000
#define NE 480000
#define NROWT 1875   // NN/16

typedef __attribute__((ext_vector_type(8))) short short8;
typedef __attribute__((ext_vector_type(4))) float floatx4;

__device__ __forceinline__ short f2bs(float f) {
    __hip_bfloat16 h = __float2bfloat16(f);
    return *reinterpret_cast<short*>(&h);
}

__device__ __forceinline__ short2 split_bf16(float f) {
    __hip_bfloat16 h = __float2bfloat16(f);          // RTNE high part
    float r = f - __bfloat162float(h);               // residual, |r| <= 2^-9 |f|
    __hip_bfloat16 l = __float2bfloat16(r);
    short2 out;
    out.x = *reinterpret_cast<short*>(&h);
    out.y = *reinterpret_cast<short*>(&l);
    return out;
}

// ---- one fused presplit of ALL weights: fp32 W[K][N] -> transposed bf16 hi/lo [Npad][K] ----
__global__ void presplit_all(const float* __restrict__ ew, const float* __restrict__ nw,
                             const float* __restrict__ m1w, const float* __restrict__ m2w,
                             const float* __restrict__ lw,
                             short* __restrict__ ew_h, short* __restrict__ ew_l,
                             short* __restrict__ nw_h, short* __restrict__ nw_l,
                             short* __restrict__ m1_h, short* __restrict__ m1_l,
                             short* __restrict__ m2_h, short* __restrict__ m2_l,
                             short* __restrict__ lw_h, short* __restrict__ lw_l)
{
    int i = blockIdx.x * 256 + threadIdx.x;
    // ranges: ew 2048 | nw 8192 | m1 98304 | m2 98304 | lw(pad16) 2048  = 208896
    if (i < 2048) {                       // ew [16][128] -> [128][16]
        int k = i >> 7, n = i & 127;
        short2 s = split_bf16(ew[i]);
        ew_h[n * 16 + k] = s.x; ew_l[n * 16 + k] = s.y;
    } else if (i < 10240) {               // nw [64][128] -> [128][64]
        int j = i - 2048;
        int k = j >> 7, n = j & 127;
        short2 s = split_bf16(nw[j]);
        nw_h[n * 64 + k] = s.x; nw_l[n * 64 + k] = s.y;
    } else if (i < 108544) {              // m1 3x[128][256] -> 3x[256][128]
        int j = i - 10240;
        int l = j >> 15, jj = j & 32767;
        int k = jj >> 8, n = jj & 255;
        short2 s = split_bf16(m1w[j]);
        m1_h[(size_t)l * 32768 + n * 128 + k] = s.x;
        m1_l[(size_t)l * 32768 + n * 128 + k] = s.y;
    } else if (i < 206848) {              // m2 3x[256][128] -> 3x[128][256]
        int j = i - 108544;
        int l = j >> 15, jj = j & 32767;
        int k = jj >> 7, n = jj & 127;
        short2 s = split_bf16(m2w[j]);
        m2_h[(size_t)l * 32768 + n * 256 + k] = s.x;
        m2_l[(size_t)l * 32768 + n * 256 + k] = s.y;
    } else if (i < 208896) {              // lw [128][10] -> [16][128] (rows>=10 zero)
        int j = i - 206848;
        int k = j >> 4, n = j & 15;
        short2 s = (n < 10) ? split_bf16(lw[k * 10 + n]) : short2{0, 0};
        lw_h[n * 128 + k] = s.x; lw_l[n * 128 + k] = s.y;
    }
}

// ---- node encoder GEMM (A fp32, split in-kernel). One 16x16 tile/wave. ----
template<int K, int N>
__launch_bounds__(256)
__global__ void gemm_a32(const float* __restrict__ A, const short* __restrict__ Bh,
                         const short* __restrict__ Bl, const float* __restrict__ bias,
                         float* __restrict__ C, int total_waves)
{
    int wave = ((blockIdx.x * 256) + threadIdx.x) >> 6;
    if (wave >= total_waves) return;
    constexpr int NT = N / 16;
    const int mt = wave / NT, nt = wave % NT;
    const int lane = threadIdx.x & 63;
    const int l15 = lane & 15, quad = lane >> 4;
    const int row = mt * 16 + l15;
    const int col = nt * 16 + l15;
    floatx4 acc = {0.f, 0.f, 0.f, 0.f};
#pragma unroll
    for (int k0 = 0; k0 < K; k0 += 32) {
        const int kb = k0 + quad * 8;
        short8 ah, al;
        const float* ap = A + (size_t)row * K + kb;
        floatx4 a0 = *(const floatx4*)ap;
        floatx4 a1 = *(const floatx4*)(ap + 4);
#pragma unroll
        for (int j = 0; j < 4; j++) {
            short2 s0 = split_bf16(a0[j]); ah[j] = s0.x; al[j] = s0.y;
            short2 s1 = split_bf16(a1[j]); ah[j + 4] = s1.x; al[j + 4] = s1.y;
        }
        short8 bh = *(const short8*)(Bh + (size_t)col * K + kb);
        short8 bl = *(const short8*)(Bl + (size_t)col * K + kb);
        acc = __builtin_amdgcn_mfma_f32_16x16x32_bf16(ah, bh, acc, 0, 0, 0);
        acc = __builtin_amdgcn_mfma_f32_16x16x32_bf16(al, bh, acc, 0, 0, 0);
        acc = __builtin_amdgcn_mfma_f32_16x16x32_bf16(ah, bl, acc, 0, 0, 0);
    }
    float bv = bias[col];
#pragma unroll
    for (int r = 0; r < 4; r++) {
        int ro = mt * 16 + quad * 4 + r;   // C/D: col=lane&15, row=quad*4+reg
        C[(size_t)ro * N + col] = acc[r] + bv;
    }
}

// ---- generic pre-split GEMM (classifier): 16 x (16*NTW) tile per wave ----
template<int K, int NTOT, int NTW, int NREAL>
__launch_bounds__(256)
__global__ void gemm_s(const short* __restrict__ Ah, const short* __restrict__ Al,
                       const short* __restrict__ Bh, const short* __restrict__ Bl,
                       const float* __restrict__ bias, float* __restrict__ C, int total_waves)
{
    int wave = ((blockIdx.x * 256) + threadIdx.x) >> 6;
    if (wave >= total_waves) return;
    constexpr int NG = NTOT / (16 * NTW);
    const int mt = wave / NG, g = wave % NG;
    const int lane = threadIdx.x & 63;
    const int l15 = lane & 15, quad = lane >> 4;
    const int row = mt * 16 + l15;
    floatx4 acc[NTW];
#pragma unroll
    for (int t = 0; t < NTW; t++) acc[t] = {0.f, 0.f, 0.f, 0.f};
#pragma unroll
    for (int k0 = 0; k0 < K; k0 += 32) {
        const int kb = k0 + quad * 8;
        short8 ah = *(const short8*)(Ah + (size_t)row * K + kb);
        short8 al = *(const short8*)(Al + (size_t)row * K + kb);
#pragma unroll
        for (int t = 0; t < NTW; t++) {
            int col = g * NTW * 16 + t * 16 + l15;
            short8 bh = *(const short8*)(Bh + (size_t)col * K + kb);
            short8 bl = *(const short8*)(Bl + (size_t)col * K + kb);
            acc[t] = __builtin_amdgcn_mfma_f32_16x16x32_bf16(ah, bh, acc[t], 0, 0, 0);
            acc[t] = __builtin_amdgcn_mfma_f32_16x16x32_bf16(al, bh, acc[t], 0, 0, 0);
            acc[t] = __builtin_amdgcn_mfma_f32_16x16x32_bf16(ah, bl, acc[t], 0, 0, 0);
        }
    }
#pragma unroll
    for (int t = 0; t < NTW; t++) {
        int col = g * NTW * 16 + t * 16 + l15;
        if (col < NREAL) {
            float bv = bias[col];
#pragma unroll
            for (int r = 0; r < 4; r++) {
                int ro = mt * 16 + quad * 4 + r;
                C[(size_t)ro * NREAL + col] = acc[t][r] + bv;
            }
        }
    }
}

// ---- edge-encoder GEMM with eidx gather: ea_csr[p] = bf16(attr[eidx[p]]) @ ew + eb ----
__launch_bounds__(256)
__global__ void gemm_ea(const float* __restrict__ edge_attr, const int2* __restrict__ se,
                        const short* __restrict__ Bh, const short* __restrict__ Bl,
                        const float* __restrict__ bias, __hip_bfloat16* __restrict__ ea)
{
    int wave = ((blockIdx.x * 256) + threadIdx.x) >> 6;   // 60000 waves exact
    const int mt = wave >> 1, g = wave & 1;
    const int lane = threadIdx.x & 63;
    const int l15 = lane & 15, quad = lane >> 4;
    const int p = mt * 16 + l15;          // CSR position
    short8 a;
    if (quad < 2) {
        int e = se[p].y;
        const float* ap = edge_attr + (size_t)e * 16 + quad * 8;
        floatx4 a0 = *(const floatx4*)ap;
        floatx4 a1 = *(const floatx4*)(ap + 4);
#pragma unroll
        for (int j = 0; j < 4; j++) { a[j] = f2bs(a0[j]); a[j + 4] = f2bs(a1[j]); }
    } else {
#pragma unroll
        for (int j = 0; j < 8; j++) a[j] = 0;
    }
    floatx4 acc[4];
#pragma unroll
    for (int t = 0; t < 4; t++) acc[t] = {0.f, 0.f, 0.f, 0.f};
#pragma unroll
    for (int t = 0; t < 4; t++) {
        int col = g * 64 + t * 16 + l15;
        short8 bh, bl;
        if (quad < 2) {
            bh = *(const short8*)(Bh + (size_t)col * 16 + quad * 8);
            bl = *(const short8*)(Bl + (size_t)col * 16 + quad * 8);
        } else {
#pragma unroll
            for (int j = 0; j < 8; j++) { bh[j] = 0; bl[j] = 0; }
        }
        acc[t] = __builtin_amdgcn_mfma_f32_16x16x32_bf16(a, bh, acc[t], 0, 0, 0);
        acc[t] = __builtin_amdgcn_mfma_f32_16x16x32_bf16(a, bl, acc[t], 0, 0, 0);
    }
#pragma unroll
    for (int t = 0; t < 4; t++) {
        int col = g * 64 + t * 16 + l15;
        float bv = bias[col];
#pragma unroll
        for (int r = 0; r < 4; r++) {
            int ro = mt * 16 + quad * 4 + r;
            ea[(size_t)ro * 128 + col] = __float2bfloat16(acc[t][r] + bv);
        }
    }
}

// ---- zero fill ----
__global__ void zero_kernel(int* __restrict__ p, int n)
{
    int i = blockIdx.x * 256 + threadIdx.x;
    if (i < n) p[i] = 0;
}

// ---- CSR build ----
__global__ void hist_kernel(const int* __restrict__ dst, int* __restrict__ count)
{
    int e = blockIdx.x * 256 + threadIdx.x;
    if (e < NE) atomicAdd(count + dst[e], 1);
}

__launch_bounds__(1024)
__global__ void scan_kernel(const int* __restrict__ count, int* __restrict__ rowptr)
{
    __shared__ int part[1024];
    const int t = threadIdx.x;
    const int CH = (NN + 1023) / 1024;          // 30
    const int base = t * CH;
    int sum = 0;
    for (int j = 0; j < CH; j++) {
        int idx = base + j;
        if (idx < NN) sum += count[idx];
    }
    part[t] = sum;
    __syncthreads();
    for (int d = 1; d < 1024; d <<= 1) {
        int v = (t >= d) ? part[t - d] : 0;
        __syncthreads();
        part[t] += v;
        __syncthreads();
    }
    int off = (t == 0) ? 0 : part[t - 1];
    for (int j = 0; j < CH; j++) {
        int idx = base + j;
        if (idx < NN) { rowptr[idx] = off; off += count[idx]; }
    }
    if (t == 1023) rowptr[NN] = part[1023];
}

__global__ void scatter_kernel(const int* __restrict__ src, const int* __restrict__ dst,
                               const int* __restrict__ rowptr, int* __restrict__ cursor,
                               int2* __restrict__ se)
{
    int e = blockIdx.x * 256 + threadIdx.x;
    if (e >= NE) return;
    int d = dst[e];
    int pos = rowptr[d] + atomicAdd(cursor + d, 1);
    se[pos] = make_int2(src[e], e);
}

// ---- fused aggregation: direct softmax (bounded logits -> no max shift), one wave/node ----
__device__ __forceinline__ void upd(float hv, float av, float tt, float& s, float& n)
{
    float g = fmaxf(hv + av, 0.f) + 1e-7f;   // msg
    float e = __expf(g * tt);                 // exp(logit); |logit| small, no shift needed
    s += e;
    n = fmaf(g, e, n);
}

__launch_bounds__(256)
__global__ void agg_kernel(const float* __restrict__ hin, const unsigned* __restrict__ ea32,
                           const int2* __restrict__ se, const int* __restrict__ rowptr,
                           const float* __restrict__ tptr, int layer,
                           short* __restrict__ Zh, short* __restrict__ Zl)
{
    int node = (blockIdx.x * 256 + threadIdx.x) >> 6;
    if (node >= NN) return;
    const int lane = threadIdx.x & 63;
    const float tt = tptr[layer];
    const float2* h2 = (const float2*)hin;
    int j = rowptr[node];
    const int end = rowptr[node + 1];
    float s0 = 0.f, s1 = 0.f, n0 = 0.f, n1 = 0.f;
    for (; j + 4 <= end; j += 4) {
        int sa = se[j].x, sb = se[j + 1].x, sc = se[j + 2].x, sd = se[j + 3].x;
        unsigned ua = ea32[(size_t)j * 64 + lane];
        unsigned ub = ea32[(size_t)(j + 1) * 64 + lane];
        unsigned uc = ea32[(size_t)(j + 2) * 64 + lane];
        unsigned ud = ea32[(size_t)(j + 3) * 64 + lane];
        float2 ha = h2[(size_t)sa * 64 + lane];
        float2 hb = h2[(size_t)sb * 64 + lane];
        float2 hc = h2[(size_t)sc * 64 + lane];
        float2 hd = h2[(size_t)sd * 64 + lane];
        upd(ha.x, __uint_as_float(ua << 16), tt, s0, n0);
        upd(ha.y, __uint_as_float(ua & 0xffff0000u), tt, s1, n1);
        upd(hb.x, __uint_as_float(ub << 16), tt, s0, n0);
        upd(hb.y, __uint_as_float(ub & 0xffff0000u), tt, s1, n1);
        upd(hc.x, __uint_as_float(uc << 16), tt, s0, n0);
        upd(hc.y, __uint_as_float(uc & 0xffff0000u), tt, s1, n1);
        upd(hd.x, __uint_as_float(ud << 16), tt, s0, n0);
        upd(hd.y, __uint_as_float(ud & 0xffff0000u), tt, s1, n1);
    }
    for (; j < end; j++) {
        int sa = se[j].x;
        unsigned ua = ea32[(size_t)j * 64 + lane];
        float2 ha = h2[(size_t)sa * 64 + lane];
        upd(ha.x, __uint_as_float(ua << 16), tt, s0, n0);
        upd(ha.y, __uint_as_float(ua & 0xffff0000u), tt, s1, n1);
    }
    float2 res = h2[(size_t)node * 64 + lane];
    float ox = n0 / (s0 + 1e-16f) + res.x;
    float oy = n1 / (s1 + 1e-16f) + res.y;
    short2 sx = split_bf16(ox), sy = split_bf16(oy);
    ((unsigned*)Zh)[(size_t)node * 64 + lane] =
        (unsigned)(unsigned short)sx.x | ((unsigned)(unsigned short)sy.x << 16);
    ((unsigned*)Zl)[(size_t)node * 64 + lane] =
        (unsigned)(unsigned short)sx.y | ((unsigned)(unsigned short)sy.y << 16);
}

// ---- fused MLP1 + LayerNorm + ReLU + split: block = 4 waves = 16 rows x 256 cols ----
__launch_bounds__(256)
__global__ void mlp1_ln(const short* __restrict__ Ah, const short* __restrict__ Al,
                        const short* __restrict__ Bh, const short* __restrict__ Bl,
                        const float* __restrict__ bias, const float* __restrict__ gam,
                        const float* __restrict__ bet,
                        short* __restrict__ Yh, short* __restrict__ Yl)
{
    __shared__ float2 part[4][16];
    __shared__ float2 stats[16];
    const int mt = blockIdx.x;               // 0..1874
    const int wv = threadIdx.x >> 6;
    const int lane = threadIdx.x & 63;
    const int l15 = lane & 15, quad = lane >> 4;
    const int row = mt * 16 + l15;
    floatx4 acc[4];
#pragma unroll
    for (int t = 0; t < 4; t++) acc[t] = {0.f, 0.f, 0.f, 0.f};
#pragma unroll
    for (int k0 = 0; k0 < 128; k0 += 32) {
        const int kb = k0 + quad * 8;
        short8 ah = *(const short8*)(Ah + (size_t)row * 128 + kb);
        short8 al = *(const short8*)(Al + (size_t)row * 128 + kb);
#pragma unroll
        for (int t = 0; t < 4; t++) {
            int col = wv * 64 + t * 16 + l15;
            short8 bh = *(const short8*)(Bh + (size_t)col * 128 + kb);
            short8 bl = *(const short8*)(Bl + (size_t)col * 128 + kb);
            acc[t] = __builtin_amdgcn_mfma_f32_16x16x32_bf16(ah, bh, acc[t], 0, 0, 0);
            acc[t] = __builtin_amdgcn_mfma_f32_16x16x32_bf16(al, bh, acc[t], 0, 0, 0);
            acc[t] = __builtin_amdgcn_mfma_f32_16x16x32_bf16(ah, bl, acc[t], 0, 0, 0);
        }
    }
    float v[4][4];
    float s1[4] = {0.f, 0.f, 0.f, 0.f}, s2[4] = {0.f, 0.f, 0.f, 0.f};
#pragma unroll
    for (int t = 0; t < 4; t++) {
        int col = wv * 64 + t * 16 + l15;
        float bv = bias[col];
#pragma unroll
        for (int r = 0; r < 4; r++) {
            float x = acc[t][r] + bv;
            v[t][r] = x; s1[r] += x; s2[r] += x * x;
        }
    }
#pragma unroll
    for (int m = 1; m <= 8; m <<= 1) {
#pragma unroll
        for (int r = 0; r < 4; r++) {
            s1[r] += __shfl_xor(s1[r], m, 64);
            s2[r] += __shfl_xor(s2[r], m, 64);
        }
    }
    if (l15 == 0) {
#pragma unroll
        for (int r = 0; r < 4; r++) part[wv][quad * 4 + r] = make_float2(s1[r], s2[r]);
    }
    __syncthreads();
    if (threadIdx.x < 16) {
        float a = 0.f, b = 0.f;
#pragma unroll
        for (int w2 = 0; w2 < 4; w2++) { a += part[w2][threadIdx.x].x; b += part[w2][threadIdx.x].y; }
        float mean = a * (1.f / 256.f);
        float var = b * (1.f / 256.f) - mean * mean;
        stats[threadIdx.x] = make_float2(mean, rsqrtf(var + 1e-5f));
    }
    __syncthreads();
    float2 st[4];
#pragma unroll
    for (int r = 0; r < 4; r++) st[r] = stats[quad * 4 + r];
#pragma unroll
    for (int t = 0; t < 4; t++) {
        int col = wv * 64 + t * 16 + l15;
        float gg = gam[col], bb = bet[col];
#pragma unroll
        for (int r = 0; r < 4; r++) {
            int ro = mt * 16 + quad * 4 + r;
            float y = fmaxf((v[t][r] - st[r].x) * st[r].y * gg + bb, 0.f);
            short2 sp = split_bf16(y);
            Yh[(size_t)ro * 256 + col] = sp.x;
            Yl[(size_t)ro * 256 + col] = sp.y;
        }
    }
}

// ---- fused MLP2 (+res) + LayerNorm + ReLU: block = 4 waves = 32 rows x 128 cols ----
// !FINAL: write h=v (fp32) and hin=relu(LN(v)) (fp32).  FINAL: write split bf16 fin only.
template<bool HAS_RES, bool FINAL>
__launch_bounds__(256)
__global__ void mlp2_ln(const short* __restrict__ Ah, const short* __restrict__ Al,
                        const short* __restrict__ Bh, const short* __restrict__ Bl,
                        const float* __restrict__ bias, const float* __restrict__ res,
                        const float* __restrict__ gam, const float* __restrict__ bet,
                        float* __restrict__ Hout, float* __restrict__ HinOut,
                        short* __restrict__ Fh, short* __restrict__ Fl)
{
    __shared__ float2 part[2][32];
    __shared__ float2 stats[32];
    const int wv = threadIdx.x >> 6;
    const int rt = wv >> 1, g = wv & 1;
    const int mt = blockIdx.x * 2 + rt;
    const bool valid = (mt < NROWT);
    const int lane = threadIdx.x & 63;
    const int l15 = lane & 15, quad = lane >> 4;
    const int row = mt * 16 + l15;
    floatx4 acc[4];
#pragma unroll
    for (int t = 0; t < 4; t++) acc[t] = {0.f, 0.f, 0.f, 0.f};
    if (valid) {
#pragma unroll
        for (int k0 = 0; k0 < 256; k0 += 32) {
            const int kb = k0 + quad * 8;
            short8 ah = *(const short8*)(Ah + (size_t)row * 256 + kb);
            short8 al = *(const short8*)(Al + (size_t)row * 256 + kb);
#pragma unroll
            for (int t = 0; t < 4; t++) {
                int col = g * 64 + t * 16 + l15;
                short8 bh = *(const short8*)(Bh + (size_t)col * 256 + kb);
                short8 bl = *(const short8*)(Bl + (size_t)col * 256 + kb);
                acc[t] = __builtin_amdgcn_mfma_f32_16x16x32_bf16(ah, bh, acc[t], 0, 0, 0);
                acc[t] = __builtin_amdgcn_mfma_f32_16x16x32_bf16(al, bh, acc[t], 0, 0, 0);
                acc[t] = __builtin_amdgcn_mfma_f32_16x16x32_bf16(ah, bl, acc[t], 0, 0, 0);
            }
        }
    }
    float v[4][4] = {};
    float s1[4] = {0.f, 0.f, 0.f, 0.f}, s2[4] = {0.f, 0.f, 0.f, 0.f};
    if (valid) {
#pragma unroll
        for (int t = 0; t < 4; t++) {
            int col = g * 64 + t * 16 + l15;
            float bv = bias[col];
#pragma unroll
            for (int r = 0; r < 4; r++) {
                int ro = mt * 16 + quad * 4 + r;
                float x = acc[t][r] + bv;
                if (HAS_RES) x += res[(size_t)ro * 128 + col];
                v[t][r] = x; s1[r] += x; s2[r] += x * x;
            }
        }
    }
#pragma unroll
    for (int m = 1; m <= 8; m <<= 1) {
#pragma unroll
        for (int r = 0; r < 4; r++) {
            s1[r] += __shfl_xor(s1[r], m, 64);
            s2[r] += __shfl_xor(s2[r], m, 64);
        }
    }
    if (l15 == 0) {
#pragma unroll
        for (int r = 0; r < 4; r++) part[g][rt * 16 + quad * 4 + r] = make_float2(s1[r], s2[r]);
    }
    __syncthreads();
    if (threadIdx.x < 32) {
        float a = part[0][threadIdx.x].x + part[1][threadIdx.x].x;
        float b = part[0][threadIdx.x].y + part[1][threadIdx.x].y;
        float mean = a * (1.f / 128.f);
        float var = b * (1.f / 128.f) - mean * mean;
        stats[threadIdx.x] = make_float2(mean, rsqrtf(var + 1e-5f));
    }
    __syncthreads();
    if (valid) {
        float2 st[4];
#pragma unroll
        for (int r = 0; r < 4; r++) st[r] = stats[rt * 16 + quad * 4 + r];
#pragma unroll
        for (int t = 0; t < 4; t++) {
            int col = g * 64 + t * 16 + l15;
            float gg = gam[col], bb = bet[col];
#pragma unroll
            for (int r = 0; r < 4; r++) {
                int ro = mt * 16 + quad * 4 + r;
                float hv = v[t][r];
                float y = fmaxf((hv - st[r].x) * st[r].y * gg + bb, 0.f);
                if (FINAL) {
                    short2 sp = split_bf16(y);
                    Fh[(size_t)ro * 128 + col] = sp.x;
                    Fl[(size_t)ro * 128 + col] = sp.y;
                } else {
                    Hout[(size_t)ro * 128 + col] = hv;
                    HinOut[(size_t)ro * 128 + col] = y;
                }
            }
        }
    }
}

extern "C" void kernel_launch(void* const* d_in, const int* in_sizes, int n_in,
                              void* d_out, int out_size, void* d_ws, size_t ws_size,
                              hipStream_t stream)
{
    const float* x         = (const float*)d_in[0];
    const float* edge_attr = (const float*)d_in[1];
    const float* nw        = (const float*)d_in[2];
    const float* nb        = (const float*)d_in[3];
    const float* ew        = (const float*)d_in[4];
    const float* eb        = (const float*)d_in[5];
    const float* m1w       = (const float*)d_in[6];
    const float* m1b       = (const float*)d_in[7];
    const float* lng       = (const float*)d_in[8];
    const float* lnb       = (const float*)d_in[9];
    const float* m2w       = (const float*)d_in[10];
    const float* m2b       = (const float*)d_in[11];
    const float* tpr       = (const float*)d_in[12];
    const float* ng        = (const float*)d_in[13];
    const float* nbb       = (const float*)d_in[14];
    const float* lw        = (const float*)d_in[15];
    const float* lb        = (const float*)d_in[16];
    const int* ei  = (const int*)d_in[17];
    const int* src = ei;
    const int* dst = ei + NE;

    // ---- workspace carve (~205 MB) ----
    char* w = (char*)d_ws;
    __hip_bfloat16* ea_csr = (__hip_bfloat16*)w; w += (size_t)NE * 128 * 2;  // 122.88 MB
    int2*  se    = (int2*)w;  w += (size_t)NE * 8;                            // 3.84 MB
    float* h     = (float*)w; w += (size_t)NN * 128 * 4;                      // 15.36 MB
    float* hin   = (float*)w; w += (size_t)NN * 128 * 4;                      // 15.36 MB
    short* zbuf_h = (short*)w;
    short* fin_h  = (short*)w; w += (size_t)NN * 128 * 2;                     // 7.68 MB (aliased)
    short* zbuf_l = (short*)w;
    short* fin_l  = (short*)w; w += (size_t)NN * 128 * 2;                     // 7.68 MB (aliased)
    short* z1s_h = (short*)w; w += (size_t)NN * 256 * 2;                      // 15.36 MB
    short* z1s_l = (short*)w; w += (size_t)NN * 256 * 2;                      // 15.36 MB
    short* ew_h = (short*)w; w += (size_t)128 * 16 * 2;
    short* ew_l = (short*)w; w += (size_t)128 * 16 * 2;
    short* nw_h = (short*)w; w += (size_t)128 * 64 * 2;
    short* nw_l = (short*)w; w += (size_t)128 * 64 * 2;
    short* m1_h = (short*)w; w += (size_t)3 * 256 * 128 * 2;
    short* m1_l = (short*)w; w += (size_t)3 * 256 * 128 * 2;
    short* m2_h = (short*)w; w += (size_t)3 * 128 * 256 * 2;
    short* m2_l = (short*)w; w += (size_t)3 * 128 * 256 * 2;
    short* lw_h = (short*)w; w += (size_t)16 * 128 * 2;
    short* lw_l = (short*)w; w += (size_t)16 * 128 * 2;
    int* count  = (int*)w;   w += (size_t)NN * 4;
    int* cursor = (int*)w;   w += (size_t)NN * 4;
    int* rowptr = (int*)w;   w += (size_t)(NN + 1) * 4;

    // ---- CSR build ----
    zero_kernel<<<(2 * NN + 255) / 256, 256, 0, stream>>>(count, 2 * NN);
    hist_kernel<<<(NE + 255) / 256, 256, 0, stream>>>(dst, count);
    scan_kernel<<<1, 1024, 0, stream>>>(count, rowptr);
    scatter_kernel<<<(NE + 255) / 256, 256, 0, stream>>>(src, dst, rowptr, cursor, se);

    // ---- weight pre-split (one kernel) ----
    presplit_all<<<(208896 + 255) / 256, 256, 0, stream>>>(
        ew, nw, m1w, m2w, lw, ew_h, ew_l, nw_h, nw_l, m1_h, m1_l, m2_h, m2_l, lw_h, lw_l);

    // ---- edge encoder (gathered, CSR-ordered) + node encoder ----
    gemm_ea<<<(NE / 16) * 2 / 4, 256, 0, stream>>>(edge_attr, se, ew_h, ew_l, eb, ea_csr);
    gemm_a32<64, 128><<<(NN / 16) * 8 / 4, 256, 0, stream>>>(x, nw_h, nw_l, nb, h, (NN / 16) * 8);

    const unsigned* ea32 = (const unsigned*)ea_csr;
    for (int layer = 0; layer < 3; ++layer) {
        const float* hi = (layer == 0) ? h : hin;
        agg_kernel<<<(NN + 3) / 4, 256, 0, stream>>>(hi, ea32, se, rowptr, tpr, layer,
                                                     zbuf_h, zbuf_l);
        mlp1_ln<<<NROWT, 256, 0, stream>>>(
            zbuf_h, zbuf_l, m1_h + (size_t)layer * 32768, m1_l + (size_t)layer * 32768,
            m1b + layer * 256, lng + layer * 256, lnb + layer * 256, z1s_h, z1s_l);
        if (layer == 0) {
            mlp2_ln<false, false><<<(NROWT + 1) / 2, 256, 0, stream>>>(
                z1s_h, z1s_l, m2_h, m2_l, m2b, nullptr,
                ng + 128, nbb + 128, h, hin, nullptr, nullptr);
        } else if (layer == 1) {
            mlp2_ln<true, false><<<(NROWT + 1) / 2, 256, 0, stream>>>(
                z1s_h, z1s_l, m2_h + 32768, m2_l + 32768, m2b + 128, h,
                ng + 256, nbb + 256, h, hin, nullptr, nullptr);
        } else {
            mlp2_ln<true, true><<<(NROWT + 1) / 2, 256, 0, stream>>>(
                z1s_h, z1s_l, m2_h + 65536, m2_l + 65536, m2b + 256, h,
                ng, nbb, nullptr, nullptr, fin_h, fin_l);
        }
    }
    // classifier
    gemm_s<128, 16, 1, 10><<<((NN / 16) + 3) / 4, 256, 0, stream>>>(
        fin_h, fin_l, lw_h, lw_l, lb, (float*)d_out, NN / 16);
}

// Round 8
// 661.037 us; speedup vs baseline: 1.3910x; 1.0377x over previous
//
#include <hip/hip_runtime.h>
#include <hip/hip_bf16.h>

#define NN 30000
#define NE 480000
#define NROWT 1875   // NN/16

typedef __attribute__((ext_vector_type(8))) short short8;
typedef __attribute__((ext_vector_type(4))) float floatx4;

__device__ __forceinline__ short f2bs(float f) {
    __hip_bfloat16 h = __float2bfloat16(f);
    return *reinterpret_cast<short*>(&h);
}

__device__ __forceinline__ short2 split_bf16(float f) {
    __hip_bfloat16 h = __float2bfloat16(f);          // RTNE high part
    float r = f - __bfloat162float(h);               // residual, |r| <= 2^-9 |f|
    __hip_bfloat16 l = __float2bfloat16(r);
    short2 out;
    out.x = *reinterpret_cast<short*>(&h);
    out.y = *reinterpret_cast<short*>(&l);
    return out;
}

// ---- one fused presplit of ALL weights: fp32 W[K][N] -> transposed bf16 hi/lo [Npad][K] ----
__global__ void presplit_all(const float* __restrict__ ew, const float* __restrict__ nw,
                             const float* __restrict__ m1w, const float* __restrict__ m2w,
                             const float* __restrict__ lw,
                             short* __restrict__ ew_h, short* __restrict__ ew_l,
                             short* __restrict__ nw_h, short* __restrict__ nw_l,
                             short* __restrict__ m1_h, short* __restrict__ m1_l,
                             short* __restrict__ m2_h, short* __restrict__ m2_l,
                             short* __restrict__ lw_h, short* __restrict__ lw_l)
{
    int i = blockIdx.x * 256 + threadIdx.x;
    if (i < 2048) {                       // ew [16][128] -> [128][16]
        int k = i >> 7, n = i & 127;
        short2 s = split_bf16(ew[i]);
        ew_h[n * 16 + k] = s.x; ew_l[n * 16 + k] = s.y;
    } else if (i < 10240) {               // nw [64][128] -> [128][64]
        int j = i - 2048;
        int k = j >> 7, n = j & 127;
        short2 s = split_bf16(nw[j]);
        nw_h[n * 64 + k] = s.x; nw_l[n * 64 + k] = s.y;
    } else if (i < 108544) {              // m1 3x[128][256] -> 3x[256][128]
        int j = i - 10240;
        int l = j >> 15, jj = j & 32767;
        int k = jj >> 8, n = jj & 255;
        short2 s = split_bf16(m1w[j]);
        m1_h[(size_t)l * 32768 + n * 128 + k] = s.x;
        m1_l[(size_t)l * 32768 + n * 128 + k] = s.y;
    } else if (i < 206848) {              // m2 3x[256][128] -> 3x[128][256]
        int j = i - 108544;
        int l = j >> 15, jj = j & 32767;
        int k = jj >> 7, n = jj & 127;
        short2 s = split_bf16(m2w[j]);
        m2_h[(size_t)l * 32768 + n * 256 + k] = s.x;
        m2_l[(size_t)l * 32768 + n * 256 + k] = s.y;
    } else if (i < 208896) {              // lw [128][10] -> [16][128] (rows>=10 zero)
        int j = i - 206848;
        int k = j >> 4, n = j & 15;
        short2 s = (n < 10) ? split_bf16(lw[k * 10 + n]) : short2{0, 0};
        lw_h[n * 128 + k] = s.x; lw_l[n * 128 + k] = s.y;
    }
}

// ---- node encoder GEMM (A fp32, split in-kernel). One 16x16 tile/wave. ----
template<int K, int N>
__launch_bounds__(256)
__global__ void gemm_a32(const float* __restrict__ A, const short* __restrict__ Bh,
                         const short* __restrict__ Bl, const float* __restrict__ bias,
                         float* __restrict__ C, int total_waves)
{
    int wave = ((blockIdx.x * 256) + threadIdx.x) >> 6;
    if (wave >= total_waves) return;
    constexpr int NT = N / 16;
    const int mt = wave / NT, nt = wave % NT;
    const int lane = threadIdx.x & 63;
    const int l15 = lane & 15, quad = lane >> 4;
    const int row = mt * 16 + l15;
    const int col = nt * 16 + l15;
    floatx4 acc = {0.f, 0.f, 0.f, 0.f};
#pragma unroll
    for (int k0 = 0; k0 < K; k0 += 32) {
        const int kb = k0 + quad * 8;
        short8 ah, al;
        const float* ap = A + (size_t)row * K + kb;
        floatx4 a0 = *(const floatx4*)ap;
        floatx4 a1 = *(const floatx4*)(ap + 4);
#pragma unroll
        for (int j = 0; j < 4; j++) {
            short2 s0 = split_bf16(a0[j]); ah[j] = s0.x; al[j] = s0.y;
            short2 s1 = split_bf16(a1[j]); ah[j + 4] = s1.x; al[j + 4] = s1.y;
        }
        short8 bh = *(const short8*)(Bh + (size_t)col * K + kb);
        short8 bl = *(const short8*)(Bl + (size_t)col * K + kb);
        acc = __builtin_amdgcn_mfma_f32_16x16x32_bf16(ah, bh, acc, 0, 0, 0);
        acc = __builtin_amdgcn_mfma_f32_16x16x32_bf16(al, bh, acc, 0, 0, 0);
        acc = __builtin_amdgcn_mfma_f32_16x16x32_bf16(ah, bl, acc, 0, 0, 0);
    }
    float bv = bias[col];
#pragma unroll
    for (int r = 0; r < 4; r++) {
        int ro = mt * 16 + quad * 4 + r;   // C/D: col=lane&15, row=quad*4+reg
        C[(size_t)ro * N + col] = acc[r] + bv;
    }
}

// ---- generic pre-split GEMM (classifier): 16 x (16*NTW) tile per wave ----
template<int K, int NTOT, int NTW, int NREAL>
__launch_bounds__(256)
__global__ void gemm_s(const short* __restrict__ Ah, const short* __restrict__ Al,
                       const short* __restrict__ Bh, const short* __restrict__ Bl,
                       const float* __restrict__ bias, float* __restrict__ C, int total_waves)
{
    int wave = ((blockIdx.x * 256) + threadIdx.x) >> 6;
    if (wave >= total_waves) return;
    constexpr int NG = NTOT / (16 * NTW);
    const int mt = wave / NG, g = wave % NG;
    const int lane = threadIdx.x & 63;
    const int l15 = lane & 15, quad = lane >> 4;
    const int row = mt * 16 + l15;
    floatx4 acc[NTW];
#pragma unroll
    for (int t = 0; t < NTW; t++) acc[t] = {0.f, 0.f, 0.f, 0.f};
#pragma unroll
    for (int k0 = 0; k0 < K; k0 += 32) {
        const int kb = k0 + quad * 8;
        short8 ah = *(const short8*)(Ah + (size_t)row * K + kb);
        short8 al = *(const short8*)(Al + (size_t)row * K + kb);
#pragma unroll
        for (int t = 0; t < NTW; t++) {
            int col = g * NTW * 16 + t * 16 + l15;
            short8 bh = *(const short8*)(Bh + (size_t)col * K + kb);
            short8 bl = *(const short8*)(Bl + (size_t)col * K + kb);
            acc[t] = __builtin_amdgcn_mfma_f32_16x16x32_bf16(ah, bh, acc[t], 0, 0, 0);
            acc[t] = __builtin_amdgcn_mfma_f32_16x16x32_bf16(al, bh, acc[t], 0, 0, 0);
            acc[t] = __builtin_amdgcn_mfma_f32_16x16x32_bf16(ah, bl, acc[t], 0, 0, 0);
        }
    }
#pragma unroll
    for (int t = 0; t < NTW; t++) {
        int col = g * NTW * 16 + t * 16 + l15;
        if (col < NREAL) {
            float bv = bias[col];
#pragma unroll
            for (int r = 0; r < 4; r++) {
                int ro = mt * 16 + quad * 4 + r;
                C[(size_t)ro * NREAL + col] = acc[t][r] + bv;
            }
        }
    }
}

// ---- edge-encoder GEMM: gathers attr via eidx, writes 4-edge-interleaved ea4 layout
// ea4 byte layout: group g4=j/4 -> [64 lanes][4 edges] u32 (packed bf16 pair of features 2l,2l+1)
// Block = 4 waves = 32 CSR rows x 128 cols; LDS transpose -> fully coalesced 16B stores.
__launch_bounds__(256)
__global__ void gemm_ea(const float* __restrict__ edge_attr, const int* __restrict__ eidx_csr,
                        const short* __restrict__ Bh, const short* __restrict__ Bl,
                        const float* __restrict__ bias, unsigned* __restrict__ ea4)
{
    __shared__ short tile[2][16][132];
    const int wv = threadIdx.x >> 6;
    const int sub = wv >> 1, g = wv & 1;
    const int lane = threadIdx.x & 63;
    const int l15 = lane & 15, quad = lane >> 4;
    const int p = blockIdx.x * 32 + sub * 16 + l15;
    short8 a;
    if (quad < 2) {
        int e = eidx_csr[p];
        const float* ap = edge_attr + (size_t)e * 16 + quad * 8;
        floatx4 a0 = *(const floatx4*)ap;
        floatx4 a1 = *(const floatx4*)(ap + 4);
#pragma unroll
        for (int j = 0; j < 4; j++) { a[j] = f2bs(a0[j]); a[j + 4] = f2bs(a1[j]); }
    } else {
#pragma unroll
        for (int j = 0; j < 8; j++) a[j] = 0;
    }
    floatx4 acc[4];
#pragma unroll
    for (int t = 0; t < 4; t++) acc[t] = {0.f, 0.f, 0.f, 0.f};
#pragma unroll
    for (int t = 0; t < 4; t++) {
        int col = g * 64 + t * 16 + l15;
        short8 bh, bl;
        if (quad < 2) {
            bh = *(const short8*)(Bh + (size_t)col * 16 + quad * 8);
            bl = *(const short8*)(Bl + (size_t)col * 16 + quad * 8);
        } else {
#pragma unroll
            for (int j = 0; j < 8; j++) { bh[j] = 0; bl[j] = 0; }
        }
        acc[t] = __builtin_amdgcn_mfma_f32_16x16x32_bf16(a, bh, acc[t], 0, 0, 0);
        acc[t] = __builtin_amdgcn_mfma_f32_16x16x32_bf16(a, bl, acc[t], 0, 0, 0);
    }
#pragma unroll
    for (int t = 0; t < 4; t++) {
        int col = g * 64 + t * 16 + l15;
        float bv = bias[col];
#pragma unroll
        for (int r = 0; r < 4; r++)
            tile[sub][quad * 4 + r][col] = f2bs(acc[t][r] + bv);
    }
    __syncthreads();
    // stage out: 512 chunks of 16 B, fully coalesced
#pragma unroll
    for (int c = 0; c < 2; c++) {
        int idx = threadIdx.x + 256 * c;          // 0..511
        int o = idx * 16;                          // byte offset in 8192-B block output
        int g4l = o >> 10;                         // local group 0..7
        int lp = (o & 1023) >> 4;                  // lane' 0..63
        unsigned u[4];
#pragma unroll
        for (int e = 0; e < 4; e++) {
            int rl = g4l * 4 + e;                  // local row 0..31
            u[e] = *(const unsigned*)&tile[rl >> 4][rl & 15][2 * lp];
        }
        uint4 val = make_uint4(u[0], u[1], u[2], u[3]);
        *(uint4*)((char*)ea4 + (size_t)blockIdx.x * 8192 + o) = val;
    }
}

// ---- zero fill ----
__global__ void zero_kernel(int* __restrict__ p, int n)
{
    int i = blockIdx.x * 256 + threadIdx.x;
    if (i < n) p[i] = 0;
}

// ---- CSR build ----
__global__ void hist_kernel(const int* __restrict__ dst, int* __restrict__ count)
{
    int e = blockIdx.x * 256 + threadIdx.x;
    if (e < NE) atomicAdd(count + dst[e], 1);
}

__launch_bounds__(1024)
__global__ void scan_kernel(const int* __restrict__ count, int* __restrict__ rowptr)
{
    __shared__ int part[1024];
    const int t = threadIdx.x;
    const int CH = (NN + 1023) / 1024;          // 30
    const int base = t * CH;
    int sum = 0;
    for (int j = 0; j < CH; j++) {
        int idx = base + j;
        if (idx < NN) sum += count[idx];
    }
    part[t] = sum;
    __syncthreads();
    for (int d = 1; d < 1024; d <<= 1) {
        int v = (t >= d) ? part[t - d] : 0;
        __syncthreads();
        part[t] += v;
        __syncthreads();
    }
    int off = (t == 0) ? 0 : part[t - 1];
    for (int j = 0; j < CH; j++) {
        int idx = base + j;
        if (idx < NN) { rowptr[idx] = off; off += count[idx]; }
    }
    if (t == 1023) rowptr[NN] = part[1023];
}

__global__ void scatter_kernel(const int* __restrict__ src, const int* __restrict__ dst,
                               const int* __restrict__ rowptr, int* __restrict__ cursor,
                               int* __restrict__ src_csr, int* __restrict__ eidx_csr)
{
    int e = blockIdx.x * 256 + threadIdx.x;
    if (e >= NE) return;
    int d = dst[e];
    int pos = rowptr[d] + atomicAdd(cursor + d, 1);
    src_csr[pos] = src[e];
    eidx_csr[pos] = e;
}

// ---- fused aggregation: direct softmax (bounded logits), one wave/node, ea4 vector loads ----
__device__ __forceinline__ void upd(float hv, float av, float tt, float& s, float& n)
{
    float g = fmaxf(hv + av, 0.f) + 1e-7f;   // msg
    float e = __expf(g * tt);                 // exp(logit)
    s += e;
    n = fmaf(g, e, n);
}

__launch_bounds__(256)
__global__ void agg_kernel(const float* __restrict__ hin, const uint4* __restrict__ ea4q,
                           const unsigned* __restrict__ ea4u, const int* __restrict__ src_csr,
                           const int* __restrict__ rowptr, const float* __restrict__ tptr,
                           int layer, short* __restrict__ Zh, short* __restrict__ Zl)
{
    int node = (blockIdx.x * 256 + threadIdx.x) >> 6;
    if (node >= NN) return;
    const int lane = threadIdx.x & 63;
    const float tt = tptr[layer];
    const float2* h2 = (const float2*)hin;
    int j = rowptr[node];
    const int end = rowptr[node + 1];
    float s0 = 0.f, s1 = 0.f, n0 = 0.f, n1 = 0.f;
    while (j < end && (j & 3)) {
        unsigned u = ea4u[(((size_t)(j >> 2)) << 8) + lane * 4 + (j & 3)];
        float2 ha = h2[(size_t)src_csr[j] * 64 + lane];
        upd(ha.x, __uint_as_float(u << 16), tt, s0, n0);
        upd(ha.y, __uint_as_float(u & 0xffff0000u), tt, s1, n1);
        j++;
    }
    for (; j + 4 <= end; j += 4) {
        uint4 uu = ea4q[(((size_t)(j >> 2)) << 6) + lane];
        int4 sv = *(const int4*)(src_csr + j);
        float2 ha = h2[(size_t)sv.x * 64 + lane];
        float2 hb = h2[(size_t)sv.y * 64 + lane];
        float2 hc = h2[(size_t)sv.z * 64 + lane];
        float2 hd = h2[(size_t)sv.w * 64 + lane];
        upd(ha.x, __uint_as_float(uu.x << 16), tt, s0, n0);
        upd(ha.y, __uint_as_float(uu.x & 0xffff0000u), tt, s1, n1);
        upd(hb.x, __uint_as_float(uu.y << 16), tt, s0, n0);
        upd(hb.y, __uint_as_float(uu.y & 0xffff0000u), tt, s1, n1);
        upd(hc.x, __uint_as_float(uu.z << 16), tt, s0, n0);
        upd(hc.y, __uint_as_float(uu.z & 0xffff0000u), tt, s1, n1);
        upd(hd.x, __uint_as_float(uu.w << 16), tt, s0, n0);
        upd(hd.y, __uint_as_float(uu.w & 0xffff0000u), tt, s1, n1);
    }
    for (; j < end; j++) {
        unsigned u = ea4u[(((size_t)(j >> 2)) << 8) + lane * 4 + (j & 3)];
        float2 ha = h2[(size_t)src_csr[j] * 64 + lane];
        upd(ha.x, __uint_as_float(u << 16), tt, s0, n0);
        upd(ha.y, __uint_as_float(u & 0xffff0000u), tt, s1, n1);
    }
    float2 res = h2[(size_t)node * 64 + lane];
    float ox = n0 / (s0 + 1e-16f) + res.x;
    float oy = n1 / (s1 + 1e-16f) + res.y;
    short2 sx = split_bf16(ox), sy = split_bf16(oy);
    ((unsigned*)Zh)[(size_t)node * 64 + lane] =
        (unsigned)(unsigned short)sx.x | ((unsigned)(unsigned short)sy.x << 16);
    ((unsigned*)Zl)[(size_t)node * 64 + lane] =
        (unsigned)(unsigned short)sx.y | ((unsigned)(unsigned short)sy.y << 16);
}

// ---- fully fused layer MLP: z1=z@W1+b1 -> LN -> ReLU (LDS) -> z2=@W2+b2 (+res) -> LN -> ReLU
// Block = 4 waves = 16 rows. !FINAL: write h=z2(+res) fp32 and hin=relu(LN). FINAL: split bf16 fin.
template<bool HAS_RES, bool FINAL>
__launch_bounds__(256)
__global__ void mlp_fused(const short* __restrict__ Ah, const short* __restrict__ Al,
                          const short* __restrict__ B1h, const short* __restrict__ B1l,
                          const float* __restrict__ b1, const float* __restrict__ g1,
                          const float* __restrict__ be1,
                          const short* __restrict__ B2h, const short* __restrict__ B2l,
                          const float* __restrict__ b2, const float* __restrict__ res,
                          const float* __restrict__ g2, const float* __restrict__ be2,
                          float* __restrict__ Hout, float* __restrict__ HinOut,
                          short* __restrict__ Fh, short* __restrict__ Fl)
{
    __shared__ short z1h[16][264];
    __shared__ short z1l[16][264];
    __shared__ float2 part[4][16];
    __shared__ float2 stats[16];
    const int mt = blockIdx.x;               // 0..1874
    const int wv = threadIdx.x >> 6;
    const int lane = threadIdx.x & 63;
    const int l15 = lane & 15, quad = lane >> 4;
    const int row = mt * 16 + l15;
    // ---- stage 1: z1 cols wv*64 .. wv*64+63
    floatx4 acc[4];
#pragma unroll
    for (int t = 0; t < 4; t++) acc[t] = {0.f, 0.f, 0.f, 0.f};
#pragma unroll
    for (int k0 = 0; k0 < 128; k0 += 32) {
        const int kb = k0 + quad * 8;
        short8 ah = *(const short8*)(Ah + (size_t)row * 128 + kb);
        short8 al = *(const short8*)(Al + (size_t)row * 128 + kb);
#pragma unroll
        for (int t = 0; t < 4; t++) {
            int col = wv * 64 + t * 16 + l15;
            short8 bh = *(const short8*)(B1h + (size_t)col * 128 + kb);
            short8 bl = *(const short8*)(B1l + (size_t)col * 128 + kb);
            acc[t] = __builtin_amdgcn_mfma_f32_16x16x32_bf16(ah, bh, acc[t], 0, 0, 0);
            acc[t] = __builtin_amdgcn_mfma_f32_16x16x32_bf16(al, bh, acc[t], 0, 0, 0);
            acc[t] = __builtin_amdgcn_mfma_f32_16x16x32_bf16(ah, bl, acc[t], 0, 0, 0);
        }
    }
    float v[4][4];
    float s1[4] = {0.f, 0.f, 0.f, 0.f}, s2[4] = {0.f, 0.f, 0.f, 0.f};
#pragma unroll
    for (int t = 0; t < 4; t++) {
        int col = wv * 64 + t * 16 + l15;
        float bv = b1[col];
#pragma unroll
        for (int r = 0; r < 4; r++) {
            float x = acc[t][r] + bv;
            v[t][r] = x; s1[r] += x; s2[r] += x * x;
        }
    }
#pragma unroll
    for (int m = 1; m <= 8; m <<= 1) {
#pragma unroll
        for (int r = 0; r < 4; r++) {
            s1[r] += __shfl_xor(s1[r], m, 64);
            s2[r] += __shfl_xor(s2[r], m, 64);
        }
    }
    if (l15 == 0) {
#pragma unroll
        for (int r = 0; r < 4; r++) part[wv][quad * 4 + r] = make_float2(s1[r], s2[r]);
    }
    __syncthreads();
    if (threadIdx.x < 16) {
        float a = 0.f, b = 0.f;
#pragma unroll
        for (int w2 = 0; w2 < 4; w2++) { a += part[w2][threadIdx.x].x; b += part[w2][threadIdx.x].y; }
        float mean = a * (1.f / 256.f);
        float var = b * (1.f / 256.f) - mean * mean;
        stats[threadIdx.x] = make_float2(mean, rsqrtf(var + 1e-5f));
    }
    __syncthreads();
    {
        float2 st[4];
#pragma unroll
        for (int r = 0; r < 4; r++) st[r] = stats[quad * 4 + r];
#pragma unroll
        for (int t = 0; t < 4; t++) {
            int col = wv * 64 + t * 16 + l15;
            float gg = g1[col], bb = be1[col];
#pragma unroll
            for (int r = 0; r < 4; r++) {
                float y = fmaxf((v[t][r] - st[r].x) * st[r].y * gg + bb, 0.f);
                short2 sp = split_bf16(y);
                z1h[quad * 4 + r][col] = sp.x;
                z1l[quad * 4 + r][col] = sp.y;
            }
        }
    }
    __syncthreads();
    // ---- stage 2: z2 cols wv*32 .. wv*32+31, K=256 from LDS
    floatx4 acc2[2];
#pragma unroll
    for (int t = 0; t < 2; t++) acc2[t] = {0.f, 0.f, 0.f, 0.f};
#pragma unroll
    for (int k0 = 0; k0 < 256; k0 += 32) {
        const int kb = k0 + quad * 8;
        short8 ah = *(const short8*)&z1h[l15][kb];
        short8 al = *(const short8*)&z1l[l15][kb];
#pragma unroll
        for (int t = 0; t < 2; t++) {
            int col = wv * 32 + t * 16 + l15;
            short8 bh = *(const short8*)(B2h + (size_t)col * 256 + kb);
            short8 bl = *(const short8*)(B2l + (size_t)col * 256 + kb);
            acc2[t] = __builtin_amdgcn_mfma_f32_16x16x32_bf16(ah, bh, acc2[t], 0, 0, 0);
            acc2[t] = __builtin_amdgcn_mfma_f32_16x16x32_bf16(al, bh, acc2[t], 0, 0, 0);
            acc2[t] = __builtin_amdgcn_mfma_f32_16x16x32_bf16(ah, bl, acc2[t], 0, 0, 0);
        }
    }
    float v2[2][4];
    float s1b[4] = {0.f, 0.f, 0.f, 0.f}, s2b[4] = {0.f, 0.f, 0.f, 0.f};
#pragma unroll
    for (int t = 0; t < 2; t++) {
        int col = wv * 32 + t * 16 + l15;
        float bv = b2[col];
#pragma unroll
        for (int r = 0; r < 4; r++) {
            int ro = mt * 16 + quad * 4 + r;
            float x = acc2[t][r] + bv;
            if (HAS_RES) x += res[(size_t)ro * 128 + col];
            v2[t][r] = x; s1b[r] += x; s2b[r] += x * x;
        }
    }
#pragma unroll
    for (int m = 1; m <= 8; m <<= 1) {
#pragma unroll
        for (int r = 0; r < 4; r++) {
            s1b[r] += __shfl_xor(s1b[r], m, 64);
            s2b[r] += __shfl_xor(s2b[r], m, 64);
        }
    }
    if (l15 == 0) {
#pragma unroll
        for (int r = 0; r < 4; r++) part[wv][quad * 4 + r] = make_float2(s1b[r], s2b[r]);
    }
    __syncthreads();
    if (threadIdx.x < 16) {
        float a = 0.f, b = 0.f;
#pragma unroll
        for (int w2 = 0; w2 < 4; w2++) { a += part[w2][threadIdx.x].x; b += part[w2][threadIdx.x].y; }
        float mean = a * (1.f / 128.f);
        float var = b * (1.f / 128.f) - mean * mean;
        stats[threadIdx.x] = make_float2(mean, rsqrtf(var + 1e-5f));
    }
    __syncthreads();
    {
        float2 st[4];
#pragma unroll
        for (int r = 0; r < 4; r++) st[r] = stats[quad * 4 + r];
#pragma unroll
        for (int t = 0; t < 2; t++) {
            int col = wv * 32 + t * 16 + l15;
            float gg = g2[col], bb = be2[col];
#pragma unroll
            for (int r = 0; r < 4; r++) {
                int ro = mt * 16 + quad * 4 + r;
                float x = v2[t][r];
                float y = fmaxf((x - st[r].x) * st[r].y * gg + bb, 0.f);
                if (FINAL) {
                    short2 sp = split_bf16(y);
                    Fh[(size_t)ro * 128 + col] = sp.x;
                    Fl[(size_t)ro * 128 + col] = sp.y;
                } else {
                    Hout[(size_t)ro * 128 + col] = x;
                    HinOut[(size_t)ro * 128 + col] = y;
                }
            }
        }
    }
}

extern "C" void kernel_launch(void* const* d_in, const int* in_sizes, int n_in,
                              void* d_out, int out_size, void* d_ws, size_t ws_size,
                              hipStream_t stream)
{
    const float* x         = (const float*)d_in[0];
    const float* edge_attr = (const float*)d_in[1];
    const float* nw        = (const float*)d_in[2];
    const float* nb        = (const float*)d_in[3];
    const float* ew        = (const float*)d_in[4];
    const float* eb        = (const float*)d_in[5];
    const float* m1w       = (const float*)d_in[6];
    const float* m1b       = (const float*)d_in[7];
    const float* lng       = (const float*)d_in[8];
    const float* lnb       = (const float*)d_in[9];
    const float* m2w       = (const float*)d_in[10];
    const float* m2b       = (const float*)d_in[11];
    const float* tpr       = (const float*)d_in[12];
    const float* ng        = (const float*)d_in[13];
    const float* nbb       = (const float*)d_in[14];
    const float* lw        = (const float*)d_in[15];
    const float* lb        = (const float*)d_in[16];
    const int* ei  = (const int*)d_in[17];
    const int* src = ei;
    const int* dst = ei + NE;

    // ---- workspace carve (~190 MB) ----
    char* w = (char*)d_ws;
    unsigned* ea4 = (unsigned*)w; w += (size_t)NE * 128 * 2;                  // 122.88 MB
    int* src_csr  = (int*)w; w += (size_t)NE * 4;
    int* eidx_csr = (int*)w; w += (size_t)NE * 4;
    float* h   = (float*)w; w += (size_t)NN * 128 * 4;
    float* hin = (float*)w; w += (size_t)NN * 128 * 4;
    short* zbuf_h = (short*)w; w += (size_t)NN * 128 * 2;
    short* zbuf_l = (short*)w; w += (size_t)NN * 128 * 2;
    short* fin_h  = (short*)w; w += (size_t)NN * 128 * 2;
    short* fin_l  = (short*)w; w += (size_t)NN * 128 * 2;
    short* ew_h = (short*)w; w += (size_t)128 * 16 * 2;
    short* ew_l = (short*)w; w += (size_t)128 * 16 * 2;
    short* nw_h = (short*)w; w += (size_t)128 * 64 * 2;
    short* nw_l = (short*)w; w += (size_t)128 * 64 * 2;
    short* m1_h = (short*)w; w += (size_t)3 * 256 * 128 * 2;
    short* m1_l = (short*)w; w += (size_t)3 * 256 * 128 * 2;
    short* m2_h = (short*)w; w += (size_t)3 * 128 * 256 * 2;
    short* m2_l = (short*)w; w += (size_t)3 * 128 * 256 * 2;
    short* lw_h = (short*)w; w += (size_t)16 * 128 * 2;
    short* lw_l = (short*)w; w += (size_t)16 * 128 * 2;
    int* count  = (int*)w;   w += (size_t)NN * 4;
    int* cursor = (int*)w;   w += (size_t)NN * 4;
    int* rowptr = (int*)w;   w += (size_t)(NN + 1) * 4;

    // ---- CSR build ----
    zero_kernel<<<(2 * NN + 255) / 256, 256, 0, stream>>>(count, 2 * NN);
    hist_kernel<<<(NE + 255) / 256, 256, 0, stream>>>(dst, count);
    scan_kernel<<<1, 1024, 0, stream>>>(count, rowptr);
    scatter_kernel<<<(NE + 255) / 256, 256, 0, stream>>>(src, dst, rowptr, cursor,
                                                         src_csr, eidx_csr);

    // ---- weight pre-split ----
    presplit_all<<<(208896 + 255) / 256, 256, 0, stream>>>(
        ew, nw, m1w, m2w, lw, ew_h, ew_l, nw_h, nw_l, m1_h, m1_l, m2_h, m2_l, lw_h, lw_l);

    // ---- edge encoder (gathered, 4-edge-interleaved output) + node encoder ----
    gemm_ea<<<NE / 32, 256, 0, stream>>>(edge_attr, eidx_csr, ew_h, ew_l, eb, ea4);
    gemm_a32<64, 128><<<(NN / 16) * 8 / 4, 256, 0, stream>>>(x, nw_h, nw_l, nb, h, (NN / 16) * 8);

    const uint4* ea4q = (const uint4*)ea4;
    for (int layer = 0; layer < 3; ++layer) {
        const float* hi = (layer == 0) ? h : hin;
        agg_kernel<<<NN / 4, 256, 0, stream>>>(hi, ea4q, ea4, src_csr, rowptr, tpr, layer,
                                               zbuf_h, zbuf_l);
        if (layer == 0) {
            mlp_fused<false, false><<<NROWT, 256, 0, stream>>>(
                zbuf_h, zbuf_l, m1_h, m1_l, m1b, lng, lnb,
                m2_h, m2_l, m2b, nullptr, ng + 128, nbb + 128, h, hin, nullptr, nullptr);
        } else if (layer == 1) {
            mlp_fused<true, false><<<NROWT, 256, 0, stream>>>(
                zbuf_h, zbuf_l, m1_h + 32768, m1_l + 32768, m1b + 256, lng + 256, lnb + 256,
                m2_h + 32768, m2_l + 32768, m2b + 128, h, ng + 256, nbb + 256, h, hin,
                nullptr, nullptr);
        } else {
            mlp_fused<true, true><<<NROWT, 256, 0, stream>>>(
                zbuf_h, zbuf_l, m1_h + 65536, m1_l + 65536, m1b + 512, lng + 512, lnb + 512,
                m2_h + 65536, m2_l + 65536, m2b + 256, h, ng, nbb, nullptr, nullptr,
                fin_h, fin_l);
        }
    }
    // classifier
    gemm_s<128, 16, 1, 10><<<((NN / 16) + 3) / 4, 256, 0, stream>>>(
        fin_h, fin_l, lw_h, lw_l, lb, (float*)d_out, NN / 16);
}

// Round 9
// 561.890 us; speedup vs baseline: 1.6364x; 1.1765x over previous
//
#include <hip/hip_runtime.h>
#include <hip/hip_bf16.h>

#define NN 30000
#define NE 480000
#define NROWT 1875   // NN/16

typedef __attribute__((ext_vector_type(8))) short short8;
typedef __attribute__((ext_vector_type(4))) float floatx4;

__device__ __forceinline__ short f2bs(float f) {
    __hip_bfloat16 h = __float2bfloat16(f);
    return *reinterpret_cast<short*>(&h);
}

__device__ __forceinline__ short2 split_bf16(float f) {
    __hip_bfloat16 h = __float2bfloat16(f);          // RTNE high part
    float r = f - __bfloat162float(h);               // residual, |r| <= 2^-9 |f|
    __hip_bfloat16 l = __float2bfloat16(r);
    short2 out;
    out.x = *reinterpret_cast<short*>(&h);
    out.y = *reinterpret_cast<short*>(&l);
    return out;
}

// ---- one fused presplit of ALL weights: fp32 W[K][N] -> transposed bf16 hi/lo [Npad][K] ----
__global__ void presplit_all(const float* __restrict__ ew, const float* __restrict__ nw,
                             const float* __restrict__ m1w, const float* __restrict__ m2w,
                             const float* __restrict__ lw,
                             short* __restrict__ ew_h, short* __restrict__ ew_l,
                             short* __restrict__ nw_h, short* __restrict__ nw_l,
                             short* __restrict__ m1_h, short* __restrict__ m1_l,
                             short* __restrict__ m2_h, short* __restrict__ m2_l,
                             short* __restrict__ lw_h, short* __restrict__ lw_l)
{
    int i = blockIdx.x * 256 + threadIdx.x;
    if (i < 2048) {                       // ew [16][128] -> [128][16]
        int k = i >> 7, n = i & 127;
        short2 s = split_bf16(ew[i]);
        ew_h[n * 16 + k] = s.x; ew_l[n * 16 + k] = s.y;
    } else if (i < 10240) {               // nw [64][128] -> [128][64]
        int j = i - 2048;
        int k = j >> 7, n = j & 127;
        short2 s = split_bf16(nw[j]);
        nw_h[n * 64 + k] = s.x; nw_l[n * 64 + k] = s.y;
    } else if (i < 108544) {              // m1 3x[128][256] -> 3x[256][128]
        int j = i - 10240;
        int l = j >> 15, jj = j & 32767;
        int k = jj >> 8, n = jj & 255;
        short2 s = split_bf16(m1w[j]);
        m1_h[(size_t)l * 32768 + n * 128 + k] = s.x;
        m1_l[(size_t)l * 32768 + n * 128 + k] = s.y;
    } else if (i < 206848) {              // m2 3x[256][128] -> 3x[128][256]
        int j = i - 108544;
        int l = j >> 15, jj = j & 32767;
        int k = jj >> 7, n = jj & 127;
        short2 s = split_bf16(m2w[j]);
        m2_h[(size_t)l * 32768 + n * 256 + k] = s.x;
        m2_l[(size_t)l * 32768 + n * 256 + k] = s.y;
    } else if (i < 208896) {              // lw [128][10] -> [16][128] (rows>=10 zero)
        int j = i - 206848;
        int k = j >> 4, n = j & 15;
        short2 s = (n < 10) ? split_bf16(lw[k * 10 + n]) : short2{0, 0};
        lw_h[n * 128 + k] = s.x; lw_l[n * 128 + k] = s.y;
    }
}

// ---- node encoder GEMM (A fp32, split in-kernel). One 16x16 tile/wave. ----
template<int K, int N>
__launch_bounds__(256)
__global__ void gemm_a32(const float* __restrict__ A, const short* __restrict__ Bh,
                         const short* __restrict__ Bl, const float* __restrict__ bias,
                         float* __restrict__ C, int total_waves)
{
    int wave = ((blockIdx.x * 256) + threadIdx.x) >> 6;
    if (wave >= total_waves) return;
    constexpr int NT = N / 16;
    const int mt = wave / NT, nt = wave % NT;
    const int lane = threadIdx.x & 63;
    const int l15 = lane & 15, quad = lane >> 4;
    const int row = mt * 16 + l15;
    const int col = nt * 16 + l15;
    floatx4 acc = {0.f, 0.f, 0.f, 0.f};
#pragma unroll
    for (int k0 = 0; k0 < K; k0 += 32) {
        const int kb = k0 + quad * 8;
        short8 ah, al;
        const float* ap = A + (size_t)row * K + kb;
        floatx4 a0 = *(const floatx4*)ap;
        floatx4 a1 = *(const floatx4*)(ap + 4);
#pragma unroll
        for (int j = 0; j < 4; j++) {
            short2 s0 = split_bf16(a0[j]); ah[j] = s0.x; al[j] = s0.y;
            short2 s1 = split_bf16(a1[j]); ah[j + 4] = s1.x; al[j + 4] = s1.y;
        }
        short8 bh = *(const short8*)(Bh + (size_t)col * K + kb);
        short8 bl = *(const short8*)(Bl + (size_t)col * K + kb);
        acc = __builtin_amdgcn_mfma_f32_16x16x32_bf16(ah, bh, acc, 0, 0, 0);
        acc = __builtin_amdgcn_mfma_f32_16x16x32_bf16(al, bh, acc, 0, 0, 0);
        acc = __builtin_amdgcn_mfma_f32_16x16x32_bf16(ah, bl, acc, 0, 0, 0);
    }
    float bv = bias[col];
#pragma unroll
    for (int r = 0; r < 4; r++) {
        int ro = mt * 16 + quad * 4 + r;   // C/D: col=lane&15, row=quad*4+reg
        C[(size_t)ro * N + col] = acc[r] + bv;
    }
}

// ---- generic pre-split GEMM (classifier): 16 x (16*NTW) tile per wave ----
template<int K, int NTOT, int NTW, int NREAL>
__launch_bounds__(256)
__global__ void gemm_s(const short* __restrict__ Ah, const short* __restrict__ Al,
                       const short* __restrict__ Bh, const short* __restrict__ Bl,
                       const float* __restrict__ bias, float* __restrict__ C, int total_waves)
{
    int wave = ((blockIdx.x * 256) + threadIdx.x) >> 6;
    if (wave >= total_waves) return;
    constexpr int NG = NTOT / (16 * NTW);
    const int mt = wave / NG, g = wave % NG;
    const int lane = threadIdx.x & 63;
    const int l15 = lane & 15, quad = lane >> 4;
    const int row = mt * 16 + l15;
    floatx4 acc[NTW];
#pragma unroll
    for (int t = 0; t < NTW; t++) acc[t] = {0.f, 0.f, 0.f, 0.f};
#pragma unroll
    for (int k0 = 0; k0 < K; k0 += 32) {
        const int kb = k0 + quad * 8;
        short8 ah = *(const short8*)(Ah + (size_t)row * K + kb);
        short8 al = *(const short8*)(Al + (size_t)row * K + kb);
#pragma unroll
        for (int t = 0; t < NTW; t++) {
            int col = g * NTW * 16 + t * 16 + l15;
            short8 bh = *(const short8*)(Bh + (size_t)col * K + kb);
            short8 bl = *(const short8*)(Bl + (size_t)col * K + kb);
            acc[t] = __builtin_amdgcn_mfma_f32_16x16x32_bf16(ah, bh, acc[t], 0, 0, 0);
            acc[t] = __builtin_amdgcn_mfma_f32_16x16x32_bf16(al, bh, acc[t], 0, 0, 0);
            acc[t] = __builtin_amdgcn_mfma_f32_16x16x32_bf16(ah, bl, acc[t], 0, 0, 0);
        }
    }
#pragma unroll
    for (int t = 0; t < NTW; t++) {
        int col = g * NTW * 16 + t * 16 + l15;
        if (col < NREAL) {
            float bv = bias[col];
#pragma unroll
            for (int r = 0; r < 4; r++) {
                int ro = mt * 16 + quad * 4 + r;
                C[(size_t)ro * NREAL + col] = acc[t][r] + bv;
            }
        }
    }
}

// ---- edge-encoder GEMM: gathers attr via eidx, writes 4-edge-interleaved ea4 layout ----
__launch_bounds__(256)
__global__ void gemm_ea(const float* __restrict__ edge_attr, const int* __restrict__ eidx_csr,
                        const short* __restrict__ Bh, const short* __restrict__ Bl,
                        const float* __restrict__ bias, unsigned* __restrict__ ea4)
{
    __shared__ short tile[2][16][132];
    const int wv = threadIdx.x >> 6;
    const int sub = wv >> 1, g = wv & 1;
    const int lane = threadIdx.x & 63;
    const int l15 = lane & 15, quad = lane >> 4;
    const int p = blockIdx.x * 32 + sub * 16 + l15;
    short8 a;
    if (quad < 2) {
        int e = eidx_csr[p];
        const float* ap = edge_attr + (size_t)e * 16 + quad * 8;
        floatx4 a0 = *(const floatx4*)ap;
        floatx4 a1 = *(const floatx4*)(ap + 4);
#pragma unroll
        for (int j = 0; j < 4; j++) { a[j] = f2bs(a0[j]); a[j + 4] = f2bs(a1[j]); }
    } else {
#pragma unroll
        for (int j = 0; j < 8; j++) a[j] = 0;
    }
    floatx4 acc[4];
#pragma unroll
    for (int t = 0; t < 4; t++) acc[t] = {0.f, 0.f, 0.f, 0.f};
#pragma unroll
    for (int t = 0; t < 4; t++) {
        int col = g * 64 + t * 16 + l15;
        short8 bh, bl;
        if (quad < 2) {
            bh = *(const short8*)(Bh + (size_t)col * 16 + quad * 8);
            bl = *(const short8*)(Bl + (size_t)col * 16 + quad * 8);
        } else {
#pragma unroll
            for (int j = 0; j < 8; j++) { bh[j] = 0; bl[j] = 0; }
        }
        acc[t] = __builtin_amdgcn_mfma_f32_16x16x32_bf16(a, bh, acc[t], 0, 0, 0);
        acc[t] = __builtin_amdgcn_mfma_f32_16x16x32_bf16(a, bl, acc[t], 0, 0, 0);
    }
#pragma unroll
    for (int t = 0; t < 4; t++) {
        int col = g * 64 + t * 16 + l15;
        float bv = bias[col];
#pragma unroll
        for (int r = 0; r < 4; r++)
            tile[sub][quad * 4 + r][col] = f2bs(acc[t][r] + bv);
    }
    __syncthreads();
#pragma unroll
    for (int c = 0; c < 2; c++) {
        int idx = threadIdx.x + 256 * c;          // 0..511
        int o = idx * 16;
        int g4l = o >> 10;
        int lp = (o & 1023) >> 4;
        unsigned u[4];
#pragma unroll
        for (int e = 0; e < 4; e++) {
            int rl = g4l * 4 + e;
            u[e] = *(const unsigned*)&tile[rl >> 4][rl & 15][2 * lp];
        }
        uint4 val = make_uint4(u[0], u[1], u[2], u[3]);
        *(uint4*)((char*)ea4 + (size_t)blockIdx.x * 8192 + o) = val;
    }
}

// ---- zero fill ----
__global__ void zero_kernel(int* __restrict__ p, int n)
{
    int i = blockIdx.x * 256 + threadIdx.x;
    if (i < n) p[i] = 0;
}

// ---- CSR build ----
__global__ void hist_kernel(const int* __restrict__ dst, int* __restrict__ count)
{
    int e = blockIdx.x * 256 + threadIdx.x;
    if (e < NE) atomicAdd(count + dst[e], 1);
}

__launch_bounds__(1024)
__global__ void scan_kernel(const int* __restrict__ count, int* __restrict__ rowptr)
{
    __shared__ int part[1024];
    const int t = threadIdx.x;
    const int CH = (NN + 1023) / 1024;          // 30
    const int base = t * CH;
    int sum = 0;
    for (int j = 0; j < CH; j++) {
        int idx = base + j;
        if (idx < NN) sum += count[idx];
    }
    part[t] = sum;
    __syncthreads();
    for (int d = 1; d < 1024; d <<= 1) {
        int v = (t >= d) ? part[t - d] : 0;
        __syncthreads();
        part[t] += v;
        __syncthreads();
    }
    int off = (t == 0) ? 0 : part[t - 1];
    for (int j = 0; j < CH; j++) {
        int idx = base + j;
        if (idx < NN) { rowptr[idx] = off; off += count[idx]; }
    }
    if (t == 1023) rowptr[NN] = part[1023];
}

__global__ void scatter_kernel(const int* __restrict__ src, const int* __restrict__ dst,
                               const int* __restrict__ rowptr, int* __restrict__ cursor,
                               int* __restrict__ src_csr, int* __restrict__ eidx_csr)
{
    int e = blockIdx.x * 256 + threadIdx.x;
    if (e >= NE) return;
    int d = dst[e];
    int pos = rowptr[d] + atomicAdd(cursor + d, 1);
    src_csr[pos] = src[e];
    eidx_csr[pos] = e;
}

// ---- fused aggregation: direct softmax (bounded logits), one wave/node, ea4 vector loads ----
__device__ __forceinline__ void upd(float hv, float av, float tt, float& s, float& n)
{
    float g = fmaxf(hv + av, 0.f) + 1e-7f;   // msg
    float e = __expf(g * tt);                 // exp(logit)
    s += e;
    n = fmaf(g, e, n);
}

__launch_bounds__(256)
__global__ void agg_kernel(const float* __restrict__ hin, const uint4* __restrict__ ea4q,
                           const unsigned* __restrict__ ea4u, const int* __restrict__ src_csr,
                           const int* __restrict__ rowptr, const float* __restrict__ tptr,
                           int layer, short* __restrict__ Zh, short* __restrict__ Zl)
{
    int node = (blockIdx.x * 256 + threadIdx.x) >> 6;
    if (node >= NN) return;
    const int lane = threadIdx.x & 63;
    const float tt = tptr[layer];
    const float2* h2 = (const float2*)hin;
    int j = rowptr[node];
    const int end = rowptr[node + 1];
    float s0 = 0.f, s1 = 0.f, n0 = 0.f, n1 = 0.f;
    while (j < end && (j & 3)) {
        unsigned u = ea4u[(((size_t)(j >> 2)) << 8) + lane * 4 + (j & 3)];
        float2 ha = h2[(size_t)src_csr[j] * 64 + lane];
        upd(ha.x, __uint_as_float(u << 16), tt, s0, n0);
        upd(ha.y, __uint_as_float(u & 0xffff0000u), tt, s1, n1);
        j++;
    }
    for (; j + 4 <= end; j += 4) {
        uint4 uu = ea4q[(((size_t)(j >> 2)) << 6) + lane];
        int4 sv = *(const int4*)(src_csr + j);
        float2 ha = h2[(size_t)sv.x * 64 + lane];
        float2 hb = h2[(size_t)sv.y * 64 + lane];
        float2 hc = h2[(size_t)sv.z * 64 + lane];
        float2 hd = h2[(size_t)sv.w * 64 + lane];
        upd(ha.x, __uint_as_float(uu.x << 16), tt, s0, n0);
        upd(ha.y, __uint_as_float(uu.x & 0xffff0000u), tt, s1, n1);
        upd(hb.x, __uint_as_float(uu.y << 16), tt, s0, n0);
        upd(hb.y, __uint_as_float(uu.y & 0xffff0000u), tt, s1, n1);
        upd(hc.x, __uint_as_float(uu.z << 16), tt, s0, n0);
        upd(hc.y, __uint_as_float(uu.z & 0xffff0000u), tt, s1, n1);
        upd(hd.x, __uint_as_float(uu.w << 16), tt, s0, n0);
        upd(hd.y, __uint_as_float(uu.w & 0xffff0000u), tt, s1, n1);
    }
    for (; j < end; j++) {
        unsigned u = ea4u[(((size_t)(j >> 2)) << 8) + lane * 4 + (j & 3)];
        float2 ha = h2[(size_t)src_csr[j] * 64 + lane];
        upd(ha.x, __uint_as_float(u << 16), tt, s0, n0);
        upd(ha.y, __uint_as_float(u & 0xffff0000u), tt, s1, n1);
    }
    float2 res = h2[(size_t)node * 64 + lane];
    float ox = n0 / (s0 + 1e-16f) + res.x;
    float oy = n1 / (s1 + 1e-16f) + res.y;
    short2 sx = split_bf16(ox), sy = split_bf16(oy);
    ((unsigned*)Zh)[(size_t)node * 64 + lane] =
        (unsigned)(unsigned short)sx.x | ((unsigned)(unsigned short)sy.x << 16);
    ((unsigned*)Zl)[(size_t)node * 64 + lane] =
        (unsigned)(unsigned short)sx.y | ((unsigned)(unsigned short)sy.y << 16);
}

// ---- fused layer MLP v2: LDS-staged weights, wave-private LN, 4 row-tiles/block ----
// Phase 1: z1 = z@W1+b1, LN, ReLU, split -> global z1s (wave-private rows).
// Phase 2: z2 = z1@W2+b2 (+res), LN, ReLU -> h/hin (or final split).
// B1/B2 staged into 64 KB LDS in two column-halves each; all waves share.
template<bool HAS_RES, bool FINAL>
__launch_bounds__(256)
__global__ void mlp_fused(const short* __restrict__ Ah, const short* __restrict__ Al,
                          const short* __restrict__ B1h, const short* __restrict__ B1l,
                          const float* __restrict__ b1, const float* __restrict__ g1,
                          const float* __restrict__ be1,
                          const short* __restrict__ B2h, const short* __restrict__ B2l,
                          const float* __restrict__ b2, const float* __restrict__ res,
                          const float* __restrict__ g2, const float* __restrict__ be2,
                          short* __restrict__ z1h, short* __restrict__ z1l,
                          float* __restrict__ Hout, float* __restrict__ HinOut,
                          short* __restrict__ Fh, short* __restrict__ Fl)
{
    __shared__ __align__(16) short lds[32768];   // 64 KB: [0:16384]=hi half, [16384:]=lo half
    const int wv = threadIdx.x >> 6;
    const int lane = threadIdx.x & 63;
    const int l15 = lane & 15, quad = lane >> 4;
    const int tile = blockIdx.x * 4 + wv;
    const bool valid = (tile < NROWT);
    const int row = tile * 16 + l15;

    // ---- phase 1: K=128, N=256 in two 128-col halves ----
    floatx4 acc[16];
#pragma unroll
    for (int t = 0; t < 16; t++) acc[t] = {0.f, 0.f, 0.f, 0.f};
    for (int hf = 0; hf < 2; hf++) {
        __syncthreads();
        {
            const float4* s1p = (const float4*)(B1h + hf * 16384);
            const float4* s2p = (const float4*)(B1l + hf * 16384);
            float4* d = (float4*)lds;
#pragma unroll
            for (int i = 0; i < 8; i++) d[threadIdx.x + 256 * i] = s1p[threadIdx.x + 256 * i];
#pragma unroll
            for (int i = 0; i < 8; i++) d[2048 + threadIdx.x + 256 * i] = s2p[threadIdx.x + 256 * i];
        }
        __syncthreads();
        if (valid) {
#pragma unroll
            for (int k0 = 0; k0 < 128; k0 += 32) {
                const int kb = k0 + quad * 8;
                short8 ah = *(const short8*)(Ah + (size_t)row * 128 + kb);
                short8 al = *(const short8*)(Al + (size_t)row * 128 + kb);
#pragma unroll
                for (int t = 0; t < 8; t++) {
                    const short* bp = lds + (t * 16 + l15) * 128 + kb;
                    short8 bh = *(const short8*)bp;
                    short8 bl = *(const short8*)(bp + 16384);
                    int ti = hf * 8 + t;
                    acc[ti] = __builtin_amdgcn_mfma_f32_16x16x32_bf16(ah, bh, acc[ti], 0, 0, 0);
                    acc[ti] = __builtin_amdgcn_mfma_f32_16x16x32_bf16(al, bh, acc[ti], 0, 0, 0);
                    acc[ti] = __builtin_amdgcn_mfma_f32_16x16x32_bf16(ah, bl, acc[ti], 0, 0, 0);
                }
            }
        }
    }
    // ---- LN1 (wave-private: wave owns full 256-col rows) ----
    if (valid) {
#pragma unroll
        for (int t = 0; t < 16; t++) {
            float bv = b1[t * 16 + l15];
#pragma unroll
            for (int r = 0; r < 4; r++) acc[t][r] += bv;
        }
        float s1[4] = {0.f, 0.f, 0.f, 0.f}, s2[4] = {0.f, 0.f, 0.f, 0.f};
#pragma unroll
        for (int t = 0; t < 16; t++)
#pragma unroll
            for (int r = 0; r < 4; r++) { s1[r] += acc[t][r]; s2[r] += acc[t][r] * acc[t][r]; }
#pragma unroll
        for (int m = 1; m <= 8; m <<= 1)
#pragma unroll
            for (int r = 0; r < 4; r++) {
                s1[r] += __shfl_xor(s1[r], m, 64);
                s2[r] += __shfl_xor(s2[r], m, 64);
            }
        float mean[4], rstd[4];
#pragma unroll
        for (int r = 0; r < 4; r++) {
            mean[r] = s1[r] * (1.f / 256.f);
            float var = s2[r] * (1.f / 256.f) - mean[r] * mean[r];
            rstd[r] = rsqrtf(var + 1e-5f);
        }
#pragma unroll
        for (int t = 0; t < 16; t++) {
            int col = t * 16 + l15;
            float gg = g1[col], bb = be1[col];
#pragma unroll
            for (int r = 0; r < 4; r++) {
                float y = fmaxf((acc[t][r] - mean[r]) * rstd[r] * gg + bb, 0.f);
                short2 sp = split_bf16(y);
                int ro = tile * 16 + quad * 4 + r;
                z1h[(size_t)ro * 256 + col] = sp.x;
                z1l[(size_t)ro * 256 + col] = sp.y;
            }
        }
    }
    // ---- phase 2: K=256, N=128 in two 64-col halves; A (z1) re-read from global (own rows) ----
    floatx4 acc2[8];
#pragma unroll
    for (int t = 0; t < 8; t++) acc2[t] = {0.f, 0.f, 0.f, 0.f};
    for (int hf = 0; hf < 2; hf++) {
        __syncthreads();
        {
            const float4* s1p = (const float4*)(B2h + hf * 16384);
            const float4* s2p = (const float4*)(B2l + hf * 16384);
            float4* d = (float4*)lds;
#pragma unroll
            for (int i = 0; i < 8; i++) d[threadIdx.x + 256 * i] = s1p[threadIdx.x + 256 * i];
#pragma unroll
            for (int i = 0; i < 8; i++) d[2048 + threadIdx.x + 256 * i] = s2p[threadIdx.x + 256 * i];
        }
        __syncthreads();
        if (valid) {
#pragma unroll
            for (int k0 = 0; k0 < 256; k0 += 32) {
                const int kb = k0 + quad * 8;
                short8 zh = *(const short8*)(z1h + (size_t)row * 256 + kb);
                short8 zl = *(const short8*)(z1l + (size_t)row * 256 + kb);
#pragma unroll
                for (int t = 0; t < 4; t++) {
                    const short* bp = lds + (t * 16 + l15) * 256 + kb;
                    short8 bh = *(const short8*)bp;
                    short8 bl = *(const short8*)(bp + 16384);
                    int ti = hf * 4 + t;
                    acc2[ti] = __builtin_amdgcn_mfma_f32_16x16x32_bf16(zh, bh, acc2[ti], 0, 0, 0);
                    acc2[ti] = __builtin_amdgcn_mfma_f32_16x16x32_bf16(zl, bh, acc2[ti], 0, 0, 0);
                    acc2[ti] = __builtin_amdgcn_mfma_f32_16x16x32_bf16(zh, bl, acc2[ti], 0, 0, 0);
                }
            }
        }
    }
    // ---- LN2 (wave-private, 128 cols) + outputs ----
    if (valid) {
#pragma unroll
        for (int t = 0; t < 8; t++) {
            int col = t * 16 + l15;
            float bv = b2[col];
#pragma unroll
            for (int r = 0; r < 4; r++) {
                acc2[t][r] += bv;
                if (HAS_RES) {
                    int ro = tile * 16 + quad * 4 + r;
                    acc2[t][r] += res[(size_t)ro * 128 + col];
                }
            }
        }
        float s1[4] = {0.f, 0.f, 0.f, 0.f}, s2[4] = {0.f, 0.f, 0.f, 0.f};
#pragma unroll
        for (int t = 0; t < 8; t++)
#pragma unroll
            for (int r = 0; r < 4; r++) { s1[r] += acc2[t][r]; s2[r] += acc2[t][r] * acc2[t][r]; }
#pragma unroll
        for (int m = 1; m <= 8; m <<= 1)
#pragma unroll
            for (int r = 0; r < 4; r++) {
                s1[r] += __shfl_xor(s1[r], m, 64);
                s2[r] += __shfl_xor(s2[r], m, 64);
            }
        float mean[4], rstd[4];
#pragma unroll
        for (int r = 0; r < 4; r++) {
            mean[r] = s1[r] * (1.f / 128.f);
            float var = s2[r] * (1.f / 128.f) - mean[r] * mean[r];
            rstd[r] = rsqrtf(var + 1e-5f);
        }
#pragma unroll
        for (int t = 0; t < 8; t++) {
            int col = t * 16 + l15;
            float gg = g2[col], bb = be2[col];
#pragma unroll
            for (int r = 0; r < 4; r++) {
                int ro = tile * 16 + quad * 4 + r;
                float x = acc2[t][r];
                float y = fmaxf((x - mean[r]) * rstd[r] * gg + bb, 0.f);
                if (FINAL) {
                    short2 sp = split_bf16(y);
                    Fh[(size_t)ro * 128 + col] = sp.x;
                    Fl[(size_t)ro * 128 + col] = sp.y;
                } else {
                    Hout[(size_t)ro * 128 + col] = x;
                    HinOut[(size_t)ro * 128 + col] = y;
                }
            }
        }
    }
}

extern "C" void kernel_launch(void* const* d_in, const int* in_sizes, int n_in,
                              void* d_out, int out_size, void* d_ws, size_t ws_size,
                              hipStream_t stream)
{
    const float* x         = (const float*)d_in[0];
    const float* edge_attr = (const float*)d_in[1];
    const float* nw        = (const float*)d_in[2];
    const float* nb        = (const float*)d_in[3];
    const float* ew        = (const float*)d_in[4];
    const float* eb        = (const float*)d_in[5];
    const float* m1w       = (const float*)d_in[6];
    const float* m1b       = (const float*)d_in[7];
    const float* lng       = (const float*)d_in[8];
    const float* lnb       = (const float*)d_in[9];
    const float* m2w       = (const float*)d_in[10];
    const float* m2b       = (const float*)d_in[11];
    const float* tpr       = (const float*)d_in[12];
    const float* ng        = (const float*)d_in[13];
    const float* nbb       = (const float*)d_in[14];
    const float* lw        = (const float*)d_in[15];
    const float* lb        = (const float*)d_in[16];
    const int* ei  = (const int*)d_in[17];
    const int* src = ei;
    const int* dst = ei + NE;

    // ---- workspace carve (~222 MB) ----
    char* w = (char*)d_ws;
    unsigned* ea4 = (unsigned*)w; w += (size_t)NE * 128 * 2;                  // 122.88 MB
    int* src_csr  = (int*)w; w += (size_t)NE * 4;
    int* eidx_csr = (int*)w; w += (size_t)NE * 4;
    float* h   = (float*)w; w += (size_t)NN * 128 * 4;
    float* hin = (float*)w; w += (size_t)NN * 128 * 4;
    short* zbuf_h = (short*)w; w += (size_t)NN * 128 * 2;
    short* zbuf_l = (short*)w; w += (size_t)NN * 128 * 2;
    short* fin_h  = (short*)w; w += (size_t)NN * 128 * 2;
    short* fin_l  = (short*)w; w += (size_t)NN * 128 * 2;
    short* z1s_h  = (short*)w; w += (size_t)NN * 256 * 2;
    short* z1s_l  = (short*)w; w += (size_t)NN * 256 * 2;
    short* ew_h = (short*)w; w += (size_t)128 * 16 * 2;
    short* ew_l = (short*)w; w += (size_t)128 * 16 * 2;
    short* nw_h = (short*)w; w += (size_t)128 * 64 * 2;
    short* nw_l = (short*)w; w += (size_t)128 * 64 * 2;
    short* m1_h = (short*)w; w += (size_t)3 * 256 * 128 * 2;
    short* m1_l = (short*)w; w += (size_t)3 * 256 * 128 * 2;
    short* m2_h = (short*)w; w += (size_t)3 * 128 * 256 * 2;
    short* m2_l = (short*)w; w += (size_t)3 * 128 * 256 * 2;
    short* lw_h = (short*)w; w += (size_t)16 * 128 * 2;
    short* lw_l = (short*)w; w += (size_t)16 * 128 * 2;
    int* count  = (int*)w;   w += (size_t)NN * 4;
    int* cursor = (int*)w;   w += (size_t)NN * 4;
    int* rowptr = (int*)w;   w += (size_t)(NN + 1) * 4;

    // ---- CSR build ----
    zero_kernel<<<(2 * NN + 255) / 256, 256, 0, stream>>>(count, 2 * NN);
    hist_kernel<<<(NE + 255) / 256, 256, 0, stream>>>(dst, count);
    scan_kernel<<<1, 1024, 0, stream>>>(count, rowptr);
    scatter_kernel<<<(NE + 255) / 256, 256, 0, stream>>>(src, dst, rowptr, cursor,
                                                         src_csr, eidx_csr);

    // ---- weight pre-split ----
    presplit_all<<<(208896 + 255) / 256, 256, 0, stream>>>(
        ew, nw, m1w, m2w, lw, ew_h, ew_l, nw_h, nw_l, m1_h, m1_l, m2_h, m2_l, lw_h, lw_l);

    // ---- edge encoder (gathered, 4-edge-interleaved output) + node encoder ----
    gemm_ea<<<NE / 32, 256, 0, stream>>>(edge_attr, eidx_csr, ew_h, ew_l, eb, ea4);
    gemm_a32<64, 128><<<(NN / 16) * 8 / 4, 256, 0, stream>>>(x, nw_h, nw_l, nb, h, (NN / 16) * 8);

    const uint4* ea4q = (const uint4*)ea4;
    const int mgrid = (NROWT + 3) / 4;   // 469 blocks, 4 row-tiles each
    for (int layer = 0; layer < 3; ++layer) {
        const float* hi = (layer == 0) ? h : hin;
        agg_kernel<<<NN / 4, 256, 0, stream>>>(hi, ea4q, ea4, src_csr, rowptr, tpr, layer,
                                               zbuf_h, zbuf_l);
        if (layer == 0) {
            mlp_fused<false, false><<<mgrid, 256, 0, stream>>>(
                zbuf_h, zbuf_l, m1_h, m1_l, m1b, lng, lnb,
                m2_h, m2_l, m2b, nullptr, ng + 128, nbb + 128,
                z1s_h, z1s_l, h, hin, nullptr, nullptr);
        } else if (layer == 1) {
            mlp_fused<true, false><<<mgrid, 256, 0, stream>>>(
                zbuf_h, zbuf_l, m1_h + 32768, m1_l + 32768, m1b + 256, lng + 256, lnb + 256,
                m2_h + 32768, m2_l + 32768, m2b + 128, h, ng + 256, nbb + 256,
                z1s_h, z1s_l, h, hin, nullptr, nullptr);
        } else {
            mlp_fused<true, true><<<mgrid, 256, 0, stream>>>(
                zbuf_h, zbuf_l, m1_h + 65536, m1_l + 65536, m1b + 512, lng + 512, lnb + 512,
                m2_h + 65536, m2_l + 65536, m2b + 256, h, ng, nbb,
                z1s_h, z1s_l, nullptr, nullptr, fin_h, fin_l);
        }
    }
    // classifier
    gemm_s<128, 16, 1, 10><<<((NN / 16) + 3) / 4, 256, 0, stream>>>(
        fin_h, fin_l, lw_h, lw_l, lb, (float*)d_out, NN / 16);
}

// Round 10
// 536.793 us; speedup vs baseline: 1.7129x; 1.0468x over previous
//
#include <hip/hip_runtime.h>
#include <hip/hip_bf16.h>

#define NN 30000
#define NE 480000
#define NROWT 1875   // NN/16

typedef __attribute__((ext_vector_type(8))) short short8;
typedef __attribute__((ext_vector_type(4))) float floatx4;

__device__ __forceinline__ short f2bs(float f) {
    __hip_bfloat16 h = __float2bfloat16(f);
    return *reinterpret_cast<short*>(&h);
}

__device__ __forceinline__ short2 split_bf16(float f) {
    __hip_bfloat16 h = __float2bfloat16(f);          // RTNE high part
    float r = f - __bfloat162float(h);               // residual, |r| <= 2^-9 |f|
    __hip_bfloat16 l = __float2bfloat16(r);
    short2 out;
    out.x = *reinterpret_cast<short*>(&h);
    out.y = *reinterpret_cast<short*>(&l);
    return out;
}

// ---- one fused presplit of ALL weights: fp32 W[K][N] -> transposed bf16 hi/lo [Npad][K] ----
__global__ void presplit_all(const float* __restrict__ ew, const float* __restrict__ nw,
                             const float* __restrict__ m1w, const float* __restrict__ m2w,
                             const float* __restrict__ lw,
                             short* __restrict__ ew_h, short* __restrict__ ew_l,
                             short* __restrict__ nw_h, short* __restrict__ nw_l,
                             short* __restrict__ m1_h, short* __restrict__ m1_l,
                             short* __restrict__ m2_h, short* __restrict__ m2_l,
                             short* __restrict__ lw_h, short* __restrict__ lw_l)
{
    int i = blockIdx.x * 256 + threadIdx.x;
    if (i < 2048) {                       // ew [16][128] -> [128][16]
        int k = i >> 7, n = i & 127;
        short2 s = split_bf16(ew[i]);
        ew_h[n * 16 + k] = s.x; ew_l[n * 16 + k] = s.y;
    } else if (i < 10240) {               // nw [64][128] -> [128][64]
        int j = i - 2048;
        int k = j >> 7, n = j & 127;
        short2 s = split_bf16(nw[j]);
        nw_h[n * 64 + k] = s.x; nw_l[n * 64 + k] = s.y;
    } else if (i < 108544) {              // m1 3x[128][256] -> 3x[256][128]
        int j = i - 10240;
        int l = j >> 15, jj = j & 32767;
        int k = jj >> 8, n = jj & 255;
        short2 s = split_bf16(m1w[j]);
        m1_h[(size_t)l * 32768 + n * 128 + k] = s.x;
        m1_l[(size_t)l * 32768 + n * 128 + k] = s.y;
    } else if (i < 206848) {              // m2 3x[256][128] -> 3x[128][256]
        int j = i - 108544;
        int l = j >> 15, jj = j & 32767;
        int k = jj >> 7, n = jj & 127;
        short2 s = split_bf16(m2w[j]);
        m2_h[(size_t)l * 32768 + n * 256 + k] = s.x;
        m2_l[(size_t)l * 32768 + n * 256 + k] = s.y;
    } else if (i < 208896) {              // lw [128][10] -> [16][128] (rows>=10 zero)
        int j = i - 206848;
        int k = j >> 4, n = j & 15;
        short2 s = (n < 10) ? split_bf16(lw[k * 10 + n]) : short2{0, 0};
        lw_h[n * 128 + k] = s.x; lw_l[n * 128 + k] = s.y;
    }
}

// ---- node encoder GEMM (A fp32, split in-kernel). One 16x16 tile/wave. ----
template<int K, int N>
__launch_bounds__(256)
__global__ void gemm_a32(const float* __restrict__ A, const short* __restrict__ Bh,
                         const short* __restrict__ Bl, const float* __restrict__ bias,
                         float* __restrict__ C, int total_waves)
{
    int wave = ((blockIdx.x * 256) + threadIdx.x) >> 6;
    if (wave >= total_waves) return;
    constexpr int NT = N / 16;
    const int mt = wave / NT, nt = wave % NT;
    const int lane = threadIdx.x & 63;
    const int l15 = lane & 15, quad = lane >> 4;
    const int row = mt * 16 + l15;
    const int col = nt * 16 + l15;
    floatx4 acc = {0.f, 0.f, 0.f, 0.f};
#pragma unroll
    for (int k0 = 0; k0 < K; k0 += 32) {
        const int kb = k0 + quad * 8;
        short8 ah, al;
        const float* ap = A + (size_t)row * K + kb;
        floatx4 a0 = *(const floatx4*)ap;
        floatx4 a1 = *(const floatx4*)(ap + 4);
#pragma unroll
        for (int j = 0; j < 4; j++) {
            short2 s0 = split_bf16(a0[j]); ah[j] = s0.x; al[j] = s0.y;
            short2 s1 = split_bf16(a1[j]); ah[j + 4] = s1.x; al[j + 4] = s1.y;
        }
        short8 bh = *(const short8*)(Bh + (size_t)col * K + kb);
        short8 bl = *(const short8*)(Bl + (size_t)col * K + kb);
        acc = __builtin_amdgcn_mfma_f32_16x16x32_bf16(ah, bh, acc, 0, 0, 0);
        acc = __builtin_amdgcn_mfma_f32_16x16x32_bf16(al, bh, acc, 0, 0, 0);
        acc = __builtin_amdgcn_mfma_f32_16x16x32_bf16(ah, bl, acc, 0, 0, 0);
    }
    float bv = bias[col];
#pragma unroll
    for (int r = 0; r < 4; r++) {
        int ro = mt * 16 + quad * 4 + r;   // C/D: col=lane&15, row=quad*4+reg
        C[(size_t)ro * N + col] = acc[r] + bv;
    }
}

// ---- generic pre-split GEMM (classifier): 16 x (16*NTW) tile per wave ----
template<int K, int NTOT, int NTW, int NREAL>
__launch_bounds__(256)
__global__ void gemm_s(const short* __restrict__ Ah, const short* __restrict__ Al,
                       const short* __restrict__ Bh, const short* __restrict__ Bl,
                       const float* __restrict__ bias, float* __restrict__ C, int total_waves)
{
    int wave = ((blockIdx.x * 256) + threadIdx.x) >> 6;
    if (wave >= total_waves) return;
    constexpr int NG = NTOT / (16 * NTW);
    const int mt = wave / NG, g = wave % NG;
    const int lane = threadIdx.x & 63;
    const int l15 = lane & 15, quad = lane >> 4;
    const int row = mt * 16 + l15;
    floatx4 acc[NTW];
#pragma unroll
    for (int t = 0; t < NTW; t++) acc[t] = {0.f, 0.f, 0.f, 0.f};
#pragma unroll
    for (int k0 = 0; k0 < K; k0 += 32) {
        const int kb = k0 + quad * 8;
        short8 ah = *(const short8*)(Ah + (size_t)row * K + kb);
        short8 al = *(const short8*)(Al + (size_t)row * K + kb);
#pragma unroll
        for (int t = 0; t < NTW; t++) {
            int col = g * NTW * 16 + t * 16 + l15;
            short8 bh = *(const short8*)(Bh + (size_t)col * K + kb);
            short8 bl = *(const short8*)(Bl + (size_t)col * K + kb);
            acc[t] = __builtin_amdgcn_mfma_f32_16x16x32_bf16(ah, bh, acc[t], 0, 0, 0);
            acc[t] = __builtin_amdgcn_mfma_f32_16x16x32_bf16(al, bh, acc[t], 0, 0, 0);
            acc[t] = __builtin_amdgcn_mfma_f32_16x16x32_bf16(ah, bl, acc[t], 0, 0, 0);
        }
    }
#pragma unroll
    for (int t = 0; t < NTW; t++) {
        int col = g * NTW * 16 + t * 16 + l15;
        if (col < NREAL) {
            float bv = bias[col];
#pragma unroll
            for (int r = 0; r < 4; r++) {
                int ro = mt * 16 + quad * 4 + r;
                C[(size_t)ro * NREAL + col] = acc[t][r] + bv;
            }
        }
    }
}

// ---- edge-encoder GEMM: gathers attr via eidx, writes 4-edge-interleaved ea4 layout ----
__launch_bounds__(256)
__global__ void gemm_ea(const float* __restrict__ edge_attr, const int* __restrict__ eidx_csr,
                        const short* __restrict__ Bh, const short* __restrict__ Bl,
                        const float* __restrict__ bias, unsigned* __restrict__ ea4)
{
    __shared__ short tile[2][16][132];
    const int wv = threadIdx.x >> 6;
    const int sub = wv >> 1, g = wv & 1;
    const int lane = threadIdx.x & 63;
    const int l15 = lane & 15, quad = lane >> 4;
    const int p = blockIdx.x * 32 + sub * 16 + l15;
    short8 a;
    if (quad < 2) {
        int e = eidx_csr[p];
        const float* ap = edge_attr + (size_t)e * 16 + quad * 8;
        floatx4 a0 = *(const floatx4*)ap;
        floatx4 a1 = *(const floatx4*)(ap + 4);
#pragma unroll
        for (int j = 0; j < 4; j++) { a[j] = f2bs(a0[j]); a[j + 4] = f2bs(a1[j]); }
    } else {
#pragma unroll
        for (int j = 0; j < 8; j++) a[j] = 0;
    }
    floatx4 acc[4];
#pragma unroll
    for (int t = 0; t < 4; t++) acc[t] = {0.f, 0.f, 0.f, 0.f};
#pragma unroll
    for (int t = 0; t < 4; t++) {
        int col = g * 64 + t * 16 + l15;
        short8 bh, bl;
        if (quad < 2) {
            bh = *(const short8*)(Bh + (size_t)col * 16 + quad * 8);
            bl = *(const short8*)(Bl + (size_t)col * 16 + quad * 8);
        } else {
#pragma unroll
            for (int j = 0; j < 8; j++) { bh[j] = 0; bl[j] = 0; }
        }
        acc[t] = __builtin_amdgcn_mfma_f32_16x16x32_bf16(a, bh, acc[t], 0, 0, 0);
        acc[t] = __builtin_amdgcn_mfma_f32_16x16x32_bf16(a, bl, acc[t], 0, 0, 0);
    }
#pragma unroll
    for (int t = 0; t < 4; t++) {
        int col = g * 64 + t * 16 + l15;
        float bv = bias[col];
#pragma unroll
        for (int r = 0; r < 4; r++)
            tile[sub][quad * 4 + r][col] = f2bs(acc[t][r] + bv);
    }
    __syncthreads();
#pragma unroll
    for (int c = 0; c < 2; c++) {
        int idx = threadIdx.x + 256 * c;          // 0..511
        int o = idx * 16;
        int g4l = o >> 10;
        int lp = (o & 1023) >> 4;
        unsigned u[4];
#pragma unroll
        for (int e = 0; e < 4; e++) {
            int rl = g4l * 4 + e;
            u[e] = *(const unsigned*)&tile[rl >> 4][rl & 15][2 * lp];
        }
        uint4 val = make_uint4(u[0], u[1], u[2], u[3]);
        *(uint4*)((char*)ea4 + (size_t)blockIdx.x * 8192 + o) = val;
    }
}

// ---- zero fill ----
__global__ void zero_kernel(int* __restrict__ p, int n)
{
    int i = blockIdx.x * 256 + threadIdx.x;
    if (i < n) p[i] = 0;
}

// ---- CSR build ----
__global__ void hist_kernel(const int* __restrict__ dst, int* __restrict__ count)
{
    int e = blockIdx.x * 256 + threadIdx.x;
    if (e < NE) atomicAdd(count + dst[e], 1);
}

__launch_bounds__(1024)
__global__ void scan_kernel(const int* __restrict__ count, int* __restrict__ rowptr)
{
    __shared__ int part[1024];
    const int t = threadIdx.x;
    const int CH = (NN + 1023) / 1024;          // 30
    const int base = t * CH;
    int sum = 0;
    for (int j = 0; j < CH; j++) {
        int idx = base + j;
        if (idx < NN) sum += count[idx];
    }
    part[t] = sum;
    __syncthreads();
    for (int d = 1; d < 1024; d <<= 1) {
        int v = (t >= d) ? part[t - d] : 0;
        __syncthreads();
        part[t] += v;
        __syncthreads();
    }
    int off = (t == 0) ? 0 : part[t - 1];
    for (int j = 0; j < CH; j++) {
        int idx = base + j;
        if (idx < NN) { rowptr[idx] = off; off += count[idx]; }
    }
    if (t == 1023) rowptr[NN] = part[1023];
}

__global__ void scatter_kernel(const int* __restrict__ src, const int* __restrict__ dst,
                               const int* __restrict__ rowptr, int* __restrict__ cursor,
                               int* __restrict__ src_csr, int* __restrict__ eidx_csr)
{
    int e = blockIdx.x * 256 + threadIdx.x;
    if (e >= NE) return;
    int d = dst[e];
    int pos = rowptr[d] + atomicAdd(cursor + d, 1);
    src_csr[pos] = src[e];
    eidx_csr[pos] = e;
}

// ---- fused aggregation: direct softmax (bounded logits), one wave/node, ea4 vector loads ----
__device__ __forceinline__ void upd(float hv, float av, float tt, float& s, float& n)
{
    float g = fmaxf(hv + av, 0.f) + 1e-7f;   // msg
    float e = __expf(g * tt);                 // exp(logit)
    s += e;
    n = fmaf(g, e, n);
}

__launch_bounds__(256)
__global__ void agg_kernel(const float* __restrict__ hin, const uint4* __restrict__ ea4q,
                           const unsigned* __restrict__ ea4u, const int* __restrict__ src_csr,
                           const int* __restrict__ rowptr, const float* __restrict__ tptr,
                           int layer, short* __restrict__ Zh, short* __restrict__ Zl)
{
    int node = (blockIdx.x * 256 + threadIdx.x) >> 6;
    if (node >= NN) return;
    const int lane = threadIdx.x & 63;
    const float tt = tptr[layer];
    const float2* h2 = (const float2*)hin;
    int j = rowptr[node];
    const int end = rowptr[node + 1];
    float s0 = 0.f, s1 = 0.f, n0 = 0.f, n1 = 0.f;
    while (j < end && (j & 3)) {
        unsigned u = ea4u[(((size_t)(j >> 2)) << 8) + lane * 4 + (j & 3)];
        float2 ha = h2[(size_t)src_csr[j] * 64 + lane];
        upd(ha.x, __uint_as_float(u << 16), tt, s0, n0);
        upd(ha.y, __uint_as_float(u & 0xffff0000u), tt, s1, n1);
        j++;
    }
    for (; j + 4 <= end; j += 4) {
        uint4 uu = ea4q[(((size_t)(j >> 2)) << 6) + lane];
        int4 sv = *(const int4*)(src_csr + j);
        float2 ha = h2[(size_t)sv.x * 64 + lane];
        float2 hb = h2[(size_t)sv.y * 64 + lane];
        float2 hc = h2[(size_t)sv.z * 64 + lane];
        float2 hd = h2[(size_t)sv.w * 64 + lane];
        upd(ha.x, __uint_as_float(uu.x << 16), tt, s0, n0);
        upd(ha.y, __uint_as_float(uu.x & 0xffff0000u), tt, s1, n1);
        upd(hb.x, __uint_as_float(uu.y << 16), tt, s0, n0);
        upd(hb.y, __uint_as_float(uu.y & 0xffff0000u), tt, s1, n1);
        upd(hc.x, __uint_as_float(uu.z << 16), tt, s0, n0);
        upd(hc.y, __uint_as_float(uu.z & 0xffff0000u), tt, s1, n1);
        upd(hd.x, __uint_as_float(uu.w << 16), tt, s0, n0);
        upd(hd.y, __uint_as_float(uu.w & 0xffff0000u), tt, s1, n1);
    }
    for (; j < end; j++) {
        unsigned u = ea4u[(((size_t)(j >> 2)) << 8) + lane * 4 + (j & 3)];
        float2 ha = h2[(size_t)src_csr[j] * 64 + lane];
        upd(ha.x, __uint_as_float(u << 16), tt, s0, n0);
        upd(ha.y, __uint_as_float(u & 0xffff0000u), tt, s1, n1);
    }
    float2 res = h2[(size_t)node * 64 + lane];
    float ox = n0 / (s0 + 1e-16f) + res.x;
    float oy = n1 / (s1 + 1e-16f) + res.y;
    short2 sx = split_bf16(ox), sy = split_bf16(oy);
    ((unsigned*)Zh)[(size_t)node * 64 + lane] =
        (unsigned)(unsigned short)sx.x | ((unsigned)(unsigned short)sy.x << 16);
    ((unsigned*)Zl)[(size_t)node * 64 + lane] =
        (unsigned)(unsigned short)sx.y | ((unsigned)(unsigned short)sy.y << 16);
}

// ---- fused layer MLP v3: LDS-staged weights with XOR bank swizzle, wave-private LN ----
// LDS unit = 16 B (8 shorts). Phase1 unit index: col*16 + (k8 ^ (col&15)), 128 cols/half.
// Phase2 unit index: col*32 + (k8 ^ (col&15)), 64 cols/half.
// Lanes of a quad then hit each 4-bank group exactly twice -> 2-way (free, m136).
template<bool HAS_RES, bool FINAL>
__launch_bounds__(256)
__global__ void mlp_fused(const short* __restrict__ Ah, const short* __restrict__ Al,
                          const short* __restrict__ B1h, const short* __restrict__ B1l,
                          const float* __restrict__ b1, const float* __restrict__ g1,
                          const float* __restrict__ be1,
                          const short* __restrict__ B2h, const short* __restrict__ B2l,
                          const float* __restrict__ b2, const float* __restrict__ res,
                          const float* __restrict__ g2, const float* __restrict__ be2,
                          short* __restrict__ z1h, short* __restrict__ z1l,
                          float* __restrict__ Hout, float* __restrict__ HinOut,
                          short* __restrict__ Fh, short* __restrict__ Fl)
{
    __shared__ __align__(16) short lds[32768];   // 64 KB: [0:16384]=hi, [16384:]=lo
    const int wv = threadIdx.x >> 6;
    const int lane = threadIdx.x & 63;
    const int l15 = lane & 15, quad = lane >> 4;
    const int tile = blockIdx.x * 4 + wv;
    const bool valid = (tile < NROWT);
    const int row = tile * 16 + l15;

    // ---- phase 1: K=128, N=256 in two 128-col halves ----
    floatx4 acc[16];
#pragma unroll
    for (int t = 0; t < 16; t++) acc[t] = {0.f, 0.f, 0.f, 0.f};
    for (int hf = 0; hf < 2; hf++) {
        __syncthreads();
        {
            const float4* s1p = (const float4*)(B1h + hf * 16384);
            const float4* s2p = (const float4*)(B1l + hf * 16384);
            float4* d = (float4*)lds;
#pragma unroll
            for (int i = 0; i < 8; i++) {
                int t8 = threadIdx.x + 256 * i;                  // 0..2047
                int col = t8 >> 4, k8 = t8 & 15;
                int unit = col * 16 + (k8 ^ (col & 15));
                d[unit] = s1p[t8];
                d[2048 + unit] = s2p[t8];
            }
        }
        __syncthreads();
        if (valid) {
#pragma unroll
            for (int k0 = 0; k0 < 128; k0 += 32) {
                const int kb = k0 + quad * 8;
                const int kb8 = kb >> 3;
                short8 ah = *(const short8*)(Ah + (size_t)row * 128 + kb);
                short8 al = *(const short8*)(Al + (size_t)row * 128 + kb);
#pragma unroll
                for (int t = 0; t < 8; t++) {
                    int col = t * 16 + l15;
                    int unit = col * 16 + (kb8 ^ (col & 15));
                    const short* bp = lds + unit * 8;
                    short8 bh = *(const short8*)bp;
                    short8 bl = *(const short8*)(bp + 16384);
                    int ti = hf * 8 + t;
                    acc[ti] = __builtin_amdgcn_mfma_f32_16x16x32_bf16(ah, bh, acc[ti], 0, 0, 0);
                    acc[ti] = __builtin_amdgcn_mfma_f32_16x16x32_bf16(al, bh, acc[ti], 0, 0, 0);
                    acc[ti] = __builtin_amdgcn_mfma_f32_16x16x32_bf16(ah, bl, acc[ti], 0, 0, 0);
                }
            }
        }
    }
    // ---- LN1 (wave-private: wave owns full 256-col rows) ----
    if (valid) {
#pragma unroll
        for (int t = 0; t < 16; t++) {
            float bv = b1[t * 16 + l15];
#pragma unroll
            for (int r = 0; r < 4; r++) acc[t][r] += bv;
        }
        float s1[4] = {0.f, 0.f, 0.f, 0.f}, s2[4] = {0.f, 0.f, 0.f, 0.f};
#pragma unroll
        for (int t = 0; t < 16; t++)
#pragma unroll
            for (int r = 0; r < 4; r++) { s1[r] += acc[t][r]; s2[r] += acc[t][r] * acc[t][r]; }
#pragma unroll
        for (int m = 1; m <= 8; m <<= 1)
#pragma unroll
            for (int r = 0; r < 4; r++) {
                s1[r] += __shfl_xor(s1[r], m, 64);
                s2[r] += __shfl_xor(s2[r], m, 64);
            }
        float mean[4], rstd[4];
#pragma unroll
        for (int r = 0; r < 4; r++) {
            mean[r] = s1[r] * (1.f / 256.f);
            float var = s2[r] * (1.f / 256.f) - mean[r] * mean[r];
            rstd[r] = rsqrtf(var + 1e-5f);
        }
#pragma unroll
        for (int t = 0; t < 16; t++) {
            int col = t * 16 + l15;
            float gg = g1[col], bb = be1[col];
#pragma unroll
            for (int r = 0; r < 4; r++) {
                float y = fmaxf((acc[t][r] - mean[r]) * rstd[r] * gg + bb, 0.f);
                short2 sp = split_bf16(y);
                int ro = tile * 16 + quad * 4 + r;
                z1h[(size_t)ro * 256 + col] = sp.x;
                z1l[(size_t)ro * 256 + col] = sp.y;
            }
        }
    }
    // ---- phase 2: K=256, N=128 in two 64-col halves; A (z1) re-read from global (own rows) ----
    floatx4 acc2[8];
#pragma unroll
    for (int t = 0; t < 8; t++) acc2[t] = {0.f, 0.f, 0.f, 0.f};
    for (int hf = 0; hf < 2; hf++) {
        __syncthreads();
        {
            const float4* s1p = (const float4*)(B2h + hf * 16384);
            const float4* s2p = (const float4*)(B2l + hf * 16384);
            float4* d = (float4*)lds;
#pragma unroll
            for (int i = 0; i < 8; i++) {
                int t8 = threadIdx.x + 256 * i;                  // 0..2047
                int col = t8 >> 5, k8 = t8 & 31;
                int unit = col * 32 + (k8 ^ (col & 15));
                d[unit] = s1p[t8];
                d[2048 + unit] = s2p[t8];
            }
        }
        __syncthreads();
        if (valid) {
#pragma unroll
            for (int k0 = 0; k0 < 256; k0 += 32) {
                const int kb = k0 + quad * 8;
                const int kb8 = kb >> 3;
                short8 zh = *(const short8*)(z1h + (size_t)row * 256 + kb);
                short8 zl = *(const short8*)(z1l + (size_t)row * 256 + kb);
#pragma unroll
                for (int t = 0; t < 4; t++) {
                    int col = t * 16 + l15;
                    int unit = col * 32 + (kb8 ^ (col & 15));
                    const short* bp = lds + unit * 8;
                    short8 bh = *(const short8*)bp;
                    short8 bl = *(const short8*)(bp + 16384);
                    int ti = hf * 4 + t;
                    acc2[ti] = __builtin_amdgcn_mfma_f32_16x16x32_bf16(zh, bh, acc2[ti], 0, 0, 0);
                    acc2[ti] = __builtin_amdgcn_mfma_f32_16x16x32_bf16(zl, bh, acc2[ti], 0, 0, 0);
                    acc2[ti] = __builtin_amdgcn_mfma_f32_16x16x32_bf16(zh, bl, acc2[ti], 0, 0, 0);
                }
            }
        }
    }
    // ---- LN2 (wave-private, 128 cols) + outputs ----
    if (valid) {
#pragma unroll
        for (int t = 0; t < 8; t++) {
            int col = t * 16 + l15;
            float bv = b2[col];
#pragma unroll
            for (int r = 0; r < 4; r++) {
                acc2[t][r] += bv;
                if (HAS_RES) {
                    int ro = tile * 16 + quad * 4 + r;
                    acc2[t][r] += res[(size_t)ro * 128 + col];
                }
            }
        }
        float s1[4] = {0.f, 0.f, 0.f, 0.f}, s2[4] = {0.f, 0.f, 0.f, 0.f};
#pragma unroll
        for (int t = 0; t < 8; t++)
#pragma unroll
            for (int r = 0; r < 4; r++) { s1[r] += acc2[t][r]; s2[r] += acc2[t][r] * acc2[t][r]; }
#pragma unroll
        for (int m = 1; m <= 8; m <<= 1)
#pragma unroll
            for (int r = 0; r < 4; r++) {
                s1[r] += __shfl_xor(s1[r], m, 64);
                s2[r] += __shfl_xor(s2[r], m, 64);
            }
        float mean[4], rstd[4];
#pragma unroll
        for (int r = 0; r < 4; r++) {
            mean[r] = s1[r] * (1.f / 128.f);
            float var = s2[r] * (1.f / 128.f) - mean[r] * mean[r];
            rstd[r] = rsqrtf(var + 1e-5f);
        }
#pragma unroll
        for (int t = 0; t < 8; t++) {
            int col = t * 16 + l15;
            float gg = g2[col], bb = be2[col];
#pragma unroll
            for (int r = 0; r < 4; r++) {
                int ro = tile * 16 + quad * 4 + r;
                float x = acc2[t][r];
                float y = fmaxf((x - mean[r]) * rstd[r] * gg + bb, 0.f);
                if (FINAL) {
                    short2 sp = split_bf16(y);
                    Fh[(size_t)ro * 128 + col] = sp.x;
                    Fl[(size_t)ro * 128 + col] = sp.y;
                } else {
                    Hout[(size_t)ro * 128 + col] = x;
                    HinOut[(size_t)ro * 128 + col] = y;
                }
            }
        }
    }
}

extern "C" void kernel_launch(void* const* d_in, const int* in_sizes, int n_in,
                              void* d_out, int out_size, void* d_ws, size_t ws_size,
                              hipStream_t stream)
{
    const float* x         = (const float*)d_in[0];
    const float* edge_attr = (const float*)d_in[1];
    const float* nw        = (const float*)d_in[2];
    const float* nb        = (const float*)d_in[3];
    const float* ew        = (const float*)d_in[4];
    const float* eb        = (const float*)d_in[5];
    const float* m1w       = (const float*)d_in[6];
    const float* m1b       = (const float*)d_in[7];
    const float* lng       = (const float*)d_in[8];
    const float* lnb       = (const float*)d_in[9];
    const float* m2w       = (const float*)d_in[10];
    const float* m2b       = (const float*)d_in[11];
    const float* tpr       = (const float*)d_in[12];
    const float* ng        = (const float*)d_in[13];
    const float* nbb       = (const float*)d_in[14];
    const float* lw        = (const float*)d_in[15];
    const float* lb        = (const float*)d_in[16];
    const int* ei  = (const int*)d_in[17];
    const int* src = ei;
    const int* dst = ei + NE;

    // ---- workspace carve (~222 MB) ----
    char* w = (char*)d_ws;
    unsigned* ea4 = (unsigned*)w; w += (size_t)NE * 128 * 2;                  // 122.88 MB
    int* src_csr  = (int*)w; w += (size_t)NE * 4;
    int* eidx_csr = (int*)w; w += (size_t)NE * 4;
    float* h   = (float*)w; w += (size_t)NN * 128 * 4;
    float* hin = (float*)w; w += (size_t)NN * 128 * 4;
    short* zbuf_h = (short*)w; w += (size_t)NN * 128 * 2;
    short* zbuf_l = (short*)w; w += (size_t)NN * 128 * 2;
    short* fin_h  = (short*)w; w += (size_t)NN * 128 * 2;
    short* fin_l  = (short*)w; w += (size_t)NN * 128 * 2;
    short* z1s_h  = (short*)w; w += (size_t)NN * 256 * 2;
    short* z1s_l  = (short*)w; w += (size_t)NN * 256 * 2;
    short* ew_h = (short*)w; w += (size_t)128 * 16 * 2;
    short* ew_l = (short*)w; w += (size_t)128 * 16 * 2;
    short* nw_h = (short*)w; w += (size_t)128 * 64 * 2;
    short* nw_l = (short*)w; w += (size_t)128 * 64 * 2;
    short* m1_h = (short*)w; w += (size_t)3 * 256 * 128 * 2;
    short* m1_l = (short*)w; w += (size_t)3 * 256 * 128 * 2;
    short* m2_h = (short*)w; w += (size_t)3 * 128 * 256 * 2;
    short* m2_l = (short*)w; w += (size_t)3 * 128 * 256 * 2;
    short* lw_h = (short*)w; w += (size_t)16 * 128 * 2;
    short* lw_l = (short*)w; w += (size_t)16 * 128 * 2;
    int* count  = (int*)w;   w += (size_t)NN * 4;
    int* cursor = (int*)w;   w += (size_t)NN * 4;
    int* rowptr = (int*)w;   w += (size_t)(NN + 1) * 4;

    // ---- CSR build ----
    zero_kernel<<<(2 * NN + 255) / 256, 256, 0, stream>>>(count, 2 * NN);
    hist_kernel<<<(NE + 255) / 256, 256, 0, stream>>>(dst, count);
    scan_kernel<<<1, 1024, 0, stream>>>(count, rowptr);
    scatter_kernel<<<(NE + 255) / 256, 256, 0, stream>>>(src, dst, rowptr, cursor,
                                                         src_csr, eidx_csr);

    // ---- weight pre-split ----
    presplit_all<<<(208896 + 255) / 256, 256, 0, stream>>>(
        ew, nw, m1w, m2w, lw, ew_h, ew_l, nw_h, nw_l, m1_h, m1_l, m2_h, m2_l, lw_h, lw_l);

    // ---- edge encoder (gathered, 4-edge-interleaved output) + node encoder ----
    gemm_ea<<<NE / 32, 256, 0, stream>>>(edge_attr, eidx_csr, ew_h, ew_l, eb, ea4);
    gemm_a32<64, 128><<<(NN / 16) * 8 / 4, 256, 0, stream>>>(x, nw_h, nw_l, nb, h, (NN / 16) * 8);

    const uint4* ea4q = (const uint4*)ea4;
    const int mgrid = (NROWT + 3) / 4;   // 469 blocks, 4 row-tiles each
    for (int layer = 0; layer < 3; ++layer) {
        const float* hi = (layer == 0) ? h : hin;
        agg_kernel<<<NN / 4, 256, 0, stream>>>(hi, ea4q, ea4, src_csr, rowptr, tpr, layer,
                                               zbuf_h, zbuf_l);
        if (layer == 0) {
            mlp_fused<false, false><<<mgrid, 256, 0, stream>>>(
                zbuf_h, zbuf_l, m1_h, m1_l, m1b, lng, lnb,
                m2_h, m2_l, m2b, nullptr, ng + 128, nbb + 128,
                z1s_h, z1s_l, h, hin, nullptr, nullptr);
        } else if (layer == 1) {
            mlp_fused<true, false><<<mgrid, 256, 0, stream>>>(
                zbuf_h, zbuf_l, m1_h + 32768, m1_l + 32768, m1b + 256, lng + 256, lnb + 256,
                m2_h + 32768, m2_l + 32768, m2b + 128, h, ng + 256, nbb + 256,
                z1s_h, z1s_l, h, hin, nullptr, nullptr);
        } else {
            mlp_fused<true, true><<<mgrid, 256, 0, stream>>>(
                zbuf_h, zbuf_l, m1_h + 65536, m1_l + 65536, m1b + 512, lng + 512, lnb + 512,
                m2_h + 65536, m2_l + 65536, m2b + 256, h, ng, nbb,
                z1s_h, z1s_l, nullptr, nullptr, fin_h, fin_l);
        }
    }
    // classifier
    gemm_s<128, 16, 1, 10><<<((NN / 16) + 3) / 4, 256, 0, stream>>>(
        fin_h, fin_l, lw_h, lw_l, lb, (float*)d_out, NN / 16);
}

// Round 11
// 507.860 us; speedup vs baseline: 1.8105x; 1.0570x over previous
//
#include <hip/hip_runtime.h>
#include <hip/hip_bf16.h>

#define NN 30000
#define NE 480000
#define NROWT 1875   // NN/16

typedef __attribute__((ext_vector_type(8))) short short8;
typedef __attribute__((ext_vector_type(4))) float floatx4;

__device__ __forceinline__ short f2bs(float f) {
    __hip_bfloat16 h = __float2bfloat16(f);
    return *reinterpret_cast<short*>(&h);
}

__device__ __forceinline__ short2 split_bf16(float f) {
    __hip_bfloat16 h = __float2bfloat16(f);          // RTNE high part
    float r = f - __bfloat162float(h);               // residual, |r| <= 2^-9 |f|
    __hip_bfloat16 l = __float2bfloat16(r);
    short2 out;
    out.x = *reinterpret_cast<short*>(&h);
    out.y = *reinterpret_cast<short*>(&l);
    return out;
}

// ---- one fused presplit of ALL weights: fp32 W[K][N] -> transposed bf16 hi/lo [Npad][K] ----
__global__ void presplit_all(const float* __restrict__ ew, const float* __restrict__ nw,
                             const float* __restrict__ m1w, const float* __restrict__ m2w,
                             const float* __restrict__ lw,
                             short* __restrict__ ew_h, short* __restrict__ ew_l,
                             short* __restrict__ nw_h, short* __restrict__ nw_l,
                             short* __restrict__ m1_h, short* __restrict__ m1_l,
                             short* __restrict__ m2_h, short* __restrict__ m2_l,
                             short* __restrict__ lw_h, short* __restrict__ lw_l)
{
    int i = blockIdx.x * 256 + threadIdx.x;
    if (i < 2048) {                       // ew [16][128] -> [128][16]
        int k = i >> 7, n = i & 127;
        short2 s = split_bf16(ew[i]);
        ew_h[n * 16 + k] = s.x; ew_l[n * 16 + k] = s.y;
    } else if (i < 10240) {               // nw [64][128] -> [128][64]
        int j = i - 2048;
        int k = j >> 7, n = j & 127;
        short2 s = split_bf16(nw[j]);
        nw_h[n * 64 + k] = s.x; nw_l[n * 64 + k] = s.y;
    } else if (i < 108544) {              // m1 3x[128][256] -> 3x[256][128]
        int j = i - 10240;
        int l = j >> 15, jj = j & 32767;
        int k = jj >> 8, n = jj & 255;
        short2 s = split_bf16(m1w[j]);
        m1_h[(size_t)l * 32768 + n * 128 + k] = s.x;
        m1_l[(size_t)l * 32768 + n * 128 + k] = s.y;
    } else if (i < 206848) {              // m2 3x[256][128] -> 3x[128][256]
        int j = i - 108544;
        int l = j >> 15, jj = j & 32767;
        int k = jj >> 7, n = jj & 127;
        short2 s = split_bf16(m2w[j]);
        m2_h[(size_t)l * 32768 + n * 256 + k] = s.x;
        m2_l[(size_t)l * 32768 + n * 256 + k] = s.y;
    } else if (i < 208896) {              // lw [128][10] -> [16][128] (rows>=10 zero)
        int j = i - 206848;
        int k = j >> 4, n = j & 15;
        short2 s = (n < 10) ? split_bf16(lw[k * 10 + n]) : short2{0, 0};
        lw_h[n * 128 + k] = s.x; lw_l[n * 128 + k] = s.y;
    }
}

// ---- node encoder GEMM (A fp32, split in-kernel). One 16x16 tile/wave.
// Also emits packed bf16 pair view hp[node][64] u32 for agg gathers.
template<int K, int N>
__launch_bounds__(256)
__global__ void gemm_a32(const float* __restrict__ A, const short* __restrict__ Bh,
                         const short* __restrict__ Bl, const float* __restrict__ bias,
                         float* __restrict__ C, unsigned* __restrict__ hp, int total_waves)
{
    int wave = ((blockIdx.x * 256) + threadIdx.x) >> 6;
    if (wave >= total_waves) return;
    constexpr int NT = N / 16;
    const int mt = wave / NT, nt = wave % NT;
    const int lane = threadIdx.x & 63;
    const int l15 = lane & 15, quad = lane >> 4;
    const int row = mt * 16 + l15;
    const int col = nt * 16 + l15;
    floatx4 acc = {0.f, 0.f, 0.f, 0.f};
#pragma unroll
    for (int k0 = 0; k0 < K; k0 += 32) {
        const int kb = k0 + quad * 8;
        short8 ah, al;
        const float* ap = A + (size_t)row * K + kb;
        floatx4 a0 = *(const floatx4*)ap;
        floatx4 a1 = *(const floatx4*)(ap + 4);
#pragma unroll
        for (int j = 0; j < 4; j++) {
            short2 s0 = split_bf16(a0[j]); ah[j] = s0.x; al[j] = s0.y;
            short2 s1 = split_bf16(a1[j]); ah[j + 4] = s1.x; al[j + 4] = s1.y;
        }
        short8 bh = *(const short8*)(Bh + (size_t)col * K + kb);
        short8 bl = *(const short8*)(Bl + (size_t)col * K + kb);
        acc = __builtin_amdgcn_mfma_f32_16x16x32_bf16(ah, bh, acc, 0, 0, 0);
        acc = __builtin_amdgcn_mfma_f32_16x16x32_bf16(al, bh, acc, 0, 0, 0);
        acc = __builtin_amdgcn_mfma_f32_16x16x32_bf16(ah, bl, acc, 0, 0, 0);
    }
    float bv = bias[col];
#pragma unroll
    for (int r = 0; r < 4; r++) {
        int ro = mt * 16 + quad * 4 + r;   // C/D: col=lane&15, row=quad*4+reg
        float v = acc[r] + bv;
        C[(size_t)ro * N + col] = v;
        int mb = (int)(unsigned short)f2bs(v);
        int ob = __shfl_xor(mb, 1, 64);
        if ((l15 & 1) == 0)
            hp[(size_t)ro * 64 + nt * 8 + (l15 >> 1)] = (unsigned)mb | ((unsigned)ob << 16);
    }
}

// ---- generic pre-split GEMM (classifier): 16 x (16*NTW) tile per wave ----
template<int K, int NTOT, int NTW, int NREAL>
__launch_bounds__(256)
__global__ void gemm_s(const short* __restrict__ Ah, const short* __restrict__ Al,
                       const short* __restrict__ Bh, const short* __restrict__ Bl,
                       const float* __restrict__ bias, float* __restrict__ C, int total_waves)
{
    int wave = ((blockIdx.x * 256) + threadIdx.x) >> 6;
    if (wave >= total_waves) return;
    constexpr int NG = NTOT / (16 * NTW);
    const int mt = wave / NG, g = wave % NG;
    const int lane = threadIdx.x & 63;
    const int l15 = lane & 15, quad = lane >> 4;
    const int row = mt * 16 + l15;
    floatx4 acc[NTW];
#pragma unroll
    for (int t = 0; t < NTW; t++) acc[t] = {0.f, 0.f, 0.f, 0.f};
#pragma unroll
    for (int k0 = 0; k0 < K; k0 += 32) {
        const int kb = k0 + quad * 8;
        short8 ah = *(const short8*)(Ah + (size_t)row * K + kb);
        short8 al = *(const short8*)(Al + (size_t)row * K + kb);
#pragma unroll
        for (int t = 0; t < NTW; t++) {
            int col = g * NTW * 16 + t * 16 + l15;
            short8 bh = *(const short8*)(Bh + (size_t)col * K + kb);
            short8 bl = *(const short8*)(Bl + (size_t)col * K + kb);
            acc[t] = __builtin_amdgcn_mfma_f32_16x16x32_bf16(ah, bh, acc[t], 0, 0, 0);
            acc[t] = __builtin_amdgcn_mfma_f32_16x16x32_bf16(al, bh, acc[t], 0, 0, 0);
            acc[t] = __builtin_amdgcn_mfma_f32_16x16x32_bf16(ah, bl, acc[t], 0, 0, 0);
        }
    }
#pragma unroll
    for (int t = 0; t < NTW; t++) {
        int col = g * NTW * 16 + t * 16 + l15;
        if (col < NREAL) {
            float bv = bias[col];
#pragma unroll
            for (int r = 0; r < 4; r++) {
                int ro = mt * 16 + quad * 4 + r;
                C[(size_t)ro * NREAL + col] = acc[t][r] + bv;
            }
        }
    }
}

// ---- edge-encoder GEMM: gathers attr via eidx, writes 4-edge-interleaved ea4 layout ----
__launch_bounds__(256)
__global__ void gemm_ea(const float* __restrict__ edge_attr, const int* __restrict__ eidx_csr,
                        const short* __restrict__ Bh, const short* __restrict__ Bl,
                        const float* __restrict__ bias, unsigned* __restrict__ ea4)
{
    __shared__ short tile[2][16][132];
    const int wv = threadIdx.x >> 6;
    const int sub = wv >> 1, g = wv & 1;
    const int lane = threadIdx.x & 63;
    const int l15 = lane & 15, quad = lane >> 4;
    const int p = blockIdx.x * 32 + sub * 16 + l15;
    short8 a;
    if (quad < 2) {
        int e = eidx_csr[p];
        const float* ap = edge_attr + (size_t)e * 16 + quad * 8;
        floatx4 a0 = *(const floatx4*)ap;
        floatx4 a1 = *(const floatx4*)(ap + 4);
#pragma unroll
        for (int j = 0; j < 4; j++) { a[j] = f2bs(a0[j]); a[j + 4] = f2bs(a1[j]); }
    } else {
#pragma unroll
        for (int j = 0; j < 8; j++) a[j] = 0;
    }
    floatx4 acc[4];
#pragma unroll
    for (int t = 0; t < 4; t++) acc[t] = {0.f, 0.f, 0.f, 0.f};
#pragma unroll
    for (int t = 0; t < 4; t++) {
        int col = g * 64 + t * 16 + l15;
        short8 bh, bl;
        if (quad < 2) {
            bh = *(const short8*)(Bh + (size_t)col * 16 + quad * 8);
            bl = *(const short8*)(Bl + (size_t)col * 16 + quad * 8);
        } else {
#pragma unroll
            for (int j = 0; j < 8; j++) { bh[j] = 0; bl[j] = 0; }
        }
        acc[t] = __builtin_amdgcn_mfma_f32_16x16x32_bf16(a, bh, acc[t], 0, 0, 0);
        acc[t] = __builtin_amdgcn_mfma_f32_16x16x32_bf16(a, bl, acc[t], 0, 0, 0);
    }
#pragma unroll
    for (int t = 0; t < 4; t++) {
        int col = g * 64 + t * 16 + l15;
        float bv = bias[col];
#pragma unroll
        for (int r = 0; r < 4; r++)
            tile[sub][quad * 4 + r][col] = f2bs(acc[t][r] + bv);
    }
    __syncthreads();
#pragma unroll
    for (int c = 0; c < 2; c++) {
        int idx = threadIdx.x + 256 * c;          // 0..511
        int o = idx * 16;
        int g4l = o >> 10;
        int lp = (o & 1023) >> 4;
        unsigned u[4];
#pragma unroll
        for (int e = 0; e < 4; e++) {
            int rl = g4l * 4 + e;
            u[e] = *(const unsigned*)&tile[rl >> 4][rl & 15][2 * lp];
        }
        uint4 val = make_uint4(u[0], u[1], u[2], u[3]);
        *(uint4*)((char*)ea4 + (size_t)blockIdx.x * 8192 + o) = val;
    }
}

// ---- zero fill ----
__global__ void zero_kernel(int* __restrict__ p, int n)
{
    int i = blockIdx.x * 256 + threadIdx.x;
    if (i < n) p[i] = 0;
}

// ---- CSR build ----
__global__ void hist_kernel(const int* __restrict__ dst, int* __restrict__ count)
{
    int e = blockIdx.x * 256 + threadIdx.x;
    if (e < NE) atomicAdd(count + dst[e], 1);
}

__launch_bounds__(1024)
__global__ void scan_kernel(const int* __restrict__ count, int* __restrict__ rowptr)
{
    __shared__ int part[1024];
    const int t = threadIdx.x;
    const int CH = (NN + 1023) / 1024;          // 30
    const int base = t * CH;
    int sum = 0;
    for (int j = 0; j < CH; j++) {
        int idx = base + j;
        if (idx < NN) sum += count[idx];
    }
    part[t] = sum;
    __syncthreads();
    for (int d = 1; d < 1024; d <<= 1) {
        int v = (t >= d) ? part[t - d] : 0;
        __syncthreads();
        part[t] += v;
        __syncthreads();
    }
    int off = (t == 0) ? 0 : part[t - 1];
    for (int j = 0; j < CH; j++) {
        int idx = base + j;
        if (idx < NN) { rowptr[idx] = off; off += count[idx]; }
    }
    if (t == 1023) rowptr[NN] = part[1023];
}

__global__ void scatter_kernel(const int* __restrict__ src, const int* __restrict__ dst,
                               const int* __restrict__ rowptr, int* __restrict__ cursor,
                               int* __restrict__ src_csr, int* __restrict__ eidx_csr)
{
    int e = blockIdx.x * 256 + threadIdx.x;
    if (e >= NE) return;
    int d = dst[e];
    int pos = rowptr[d] + atomicAdd(cursor + d, 1);
    src_csr[pos] = src[e];
    eidx_csr[pos] = e;
}

// ---- fused aggregation v2: bf16 hp gather, masked 4-edge groups (no scalar path) ----
__device__ __forceinline__ void updm(float hv, float av, float tt, float m,
                                     float& s, float& n)
{
    float g = fmaxf(hv + av, 0.f) + 1e-7f;   // msg
    float e = __expf(g * tt) * m;             // exp(logit), masked
    s += e;
    n = fmaf(g, e, n);
}

__launch_bounds__(256)
__global__ void agg_kernel(const unsigned* __restrict__ hp, const float* __restrict__ hres,
                           const uint4* __restrict__ ea4q, const int* __restrict__ src_csr,
                           const int* __restrict__ rowptr, const float* __restrict__ tptr,
                           int layer, short* __restrict__ Zh, short* __restrict__ Zl)
{
    int node = (blockIdx.x * 256 + threadIdx.x) >> 6;
    if (node >= NN) return;
    const int lane = threadIdx.x & 63;
    const float tt = tptr[layer];
    const int start = rowptr[node];
    const int end = rowptr[node + 1];
    const int g0 = start >> 2, g1 = (end + 3) >> 2;
    float s0 = 0.f, s1 = 0.f, n0 = 0.f, n1 = 0.f;
    float s0b = 0.f, s1b = 0.f, n0b = 0.f, n1b = 0.f;

#define PROC(GG, S0, S1, N0, N1)                                                   \
    {                                                                              \
        uint4 uu = ea4q[((size_t)(GG) << 6) + lane];                               \
        int4 sv = *(const int4*)(src_csr + 4 * (GG));                              \
        int jb = 4 * (GG);                                                         \
        float m0 = (jb     >= start && jb     < end) ? 1.f : 0.f;                  \
        float m1 = (jb + 1 >= start && jb + 1 < end) ? 1.f : 0.f;                  \
        float m2 = (jb + 2 >= start && jb + 2 < end) ? 1.f : 0.f;                  \
        float m3 = (jb + 3 >= start && jb + 3 < end) ? 1.f : 0.f;                  \
        unsigned ha = hp[(size_t)sv.x * 64 + lane];                                \
        unsigned hb = hp[(size_t)sv.y * 64 + lane];                                \
        unsigned hc = hp[(size_t)sv.z * 64 + lane];                                \
        unsigned hd = hp[(size_t)sv.w * 64 + lane];                                \
        updm(__uint_as_float(ha << 16), __uint_as_float(uu.x << 16), tt, m0, S0, N0); \
        updm(__uint_as_float(ha & 0xffff0000u), __uint_as_float(uu.x & 0xffff0000u), tt, m0, S1, N1); \
        updm(__uint_as_float(hb << 16), __uint_as_float(uu.y << 16), tt, m1, S0, N0); \
        updm(__uint_as_float(hb & 0xffff0000u), __uint_as_float(uu.y & 0xffff0000u), tt, m1, S1, N1); \
        updm(__uint_as_float(hc << 16), __uint_as_float(uu.z << 16), tt, m2, S0, N0); \
        updm(__uint_as_float(hc & 0xffff0000u), __uint_as_float(uu.z & 0xffff0000u), tt, m2, S1, N1); \
        updm(__uint_as_float(hd << 16), __uint_as_float(uu.w << 16), tt, m3, S0, N0); \
        updm(__uint_as_float(hd & 0xffff0000u), __uint_as_float(uu.w & 0xffff0000u), tt, m3, S1, N1); \
    }

    int g = g0;
    for (; g + 2 <= g1; g += 2) {
        PROC(g, s0, s1, n0, n1);
        PROC(g + 1, s0b, s1b, n0b, n1b);
    }
    if (g < g1) PROC(g, s0, s1, n0, n1);
#undef PROC
    s0 += s0b; s1 += s1b; n0 += n0b; n1 += n1b;

    float2 res = ((const float2*)hres)[(size_t)node * 64 + lane];
    float ox = n0 / (s0 + 1e-16f) + res.x;
    float oy = n1 / (s1 + 1e-16f) + res.y;
    short2 sx = split_bf16(ox), sy = split_bf16(oy);
    ((unsigned*)Zh)[(size_t)node * 64 + lane] =
        (unsigned)(unsigned short)sx.x | ((unsigned)(unsigned short)sy.x << 16);
    ((unsigned*)Zl)[(size_t)node * 64 + lane] =
        (unsigned)(unsigned short)sx.y | ((unsigned)(unsigned short)sy.y << 16);
}

// ---- fused layer MLP v3: LDS-staged weights with XOR bank swizzle, wave-private LN ----
// !FINAL also emits packed bf16 hp of the relu(LN) output for next layer's agg gather.
template<bool HAS_RES, bool FINAL>
__launch_bounds__(256)
__global__ void mlp_fused(const short* __restrict__ Ah, const short* __restrict__ Al,
                          const short* __restrict__ B1h, const short* __restrict__ B1l,
                          const float* __restrict__ b1, const float* __restrict__ g1,
                          const float* __restrict__ be1,
                          const short* __restrict__ B2h, const short* __restrict__ B2l,
                          const float* __restrict__ b2, const float* __restrict__ res,
                          const float* __restrict__ g2, const float* __restrict__ be2,
                          short* __restrict__ z1h, short* __restrict__ z1l,
                          float* __restrict__ Hout, float* __restrict__ HinOut,
                          unsigned* __restrict__ HP,
                          short* __restrict__ Fh, short* __restrict__ Fl)
{
    __shared__ __align__(16) short lds[32768];   // 64 KB: [0:16384]=hi, [16384:]=lo
    const int wv = threadIdx.x >> 6;
    const int lane = threadIdx.x & 63;
    const int l15 = lane & 15, quad = lane >> 4;
    const int tile = blockIdx.x * 4 + wv;
    const bool valid = (tile < NROWT);
    const int row = tile * 16 + l15;

    // ---- phase 1: K=128, N=256 in two 128-col halves ----
    floatx4 acc[16];
#pragma unroll
    for (int t = 0; t < 16; t++) acc[t] = {0.f, 0.f, 0.f, 0.f};
    for (int hf = 0; hf < 2; hf++) {
        __syncthreads();
        {
            const float4* s1p = (const float4*)(B1h + hf * 16384);
            const float4* s2p = (const float4*)(B1l + hf * 16384);
            float4* d = (float4*)lds;
#pragma unroll
            for (int i = 0; i < 8; i++) {
                int t8 = threadIdx.x + 256 * i;                  // 0..2047
                int col = t8 >> 4, k8 = t8 & 15;
                int unit = col * 16 + (k8 ^ (col & 15));
                d[unit] = s1p[t8];
                d[2048 + unit] = s2p[t8];
            }
        }
        __syncthreads();
        if (valid) {
#pragma unroll
            for (int k0 = 0; k0 < 128; k0 += 32) {
                const int kb = k0 + quad * 8;
                const int kb8 = kb >> 3;
                short8 ah = *(const short8*)(Ah + (size_t)row * 128 + kb);
                short8 al = *(const short8*)(Al + (size_t)row * 128 + kb);
#pragma unroll
                for (int t = 0; t < 8; t++) {
                    int col = t * 16 + l15;
                    int unit = col * 16 + (kb8 ^ (col & 15));
                    const short* bp = lds + unit * 8;
                    short8 bh = *(const short8*)bp;
                    short8 bl = *(const short8*)(bp + 16384);
                    int ti = hf * 8 + t;
                    acc[ti] = __builtin_amdgcn_mfma_f32_16x16x32_bf16(ah, bh, acc[ti], 0, 0, 0);
                    acc[ti] = __builtin_amdgcn_mfma_f32_16x16x32_bf16(al, bh, acc[ti], 0, 0, 0);
                    acc[ti] = __builtin_amdgcn_mfma_f32_16x16x32_bf16(ah, bl, acc[ti], 0, 0, 0);
                }
            }
        }
    }
    // ---- LN1 (wave-private: wave owns full 256-col rows) ----
    if (valid) {
#pragma unroll
        for (int t = 0; t < 16; t++) {
            float bv = b1[t * 16 + l15];
#pragma unroll
            for (int r = 0; r < 4; r++) acc[t][r] += bv;
        }
        float s1[4] = {0.f, 0.f, 0.f, 0.f}, s2[4] = {0.f, 0.f, 0.f, 0.f};
#pragma unroll
        for (int t = 0; t < 16; t++)
#pragma unroll
            for (int r = 0; r < 4; r++) { s1[r] += acc[t][r]; s2[r] += acc[t][r] * acc[t][r]; }
#pragma unroll
        for (int m = 1; m <= 8; m <<= 1)
#pragma unroll
            for (int r = 0; r < 4; r++) {
                s1[r] += __shfl_xor(s1[r], m, 64);
                s2[r] += __shfl_xor(s2[r], m, 64);
            }
        float mean[4], rstd[4];
#pragma unroll
        for (int r = 0; r < 4; r++) {
            mean[r] = s1[r] * (1.f / 256.f);
            float var = s2[r] * (1.f / 256.f) - mean[r] * mean[r];
            rstd[r] = rsqrtf(var + 1e-5f);
        }
#pragma unroll
        for (int t = 0; t < 16; t++) {
            int col = t * 16 + l15;
            float gg = g1[col], bb = be1[col];
#pragma unroll
            for (int r = 0; r < 4; r++) {
                float y = fmaxf((acc[t][r] - mean[r]) * rstd[r] * gg + bb, 0.f);
                short2 sp = split_bf16(y);
                int ro = tile * 16 + quad * 4 + r;
                z1h[(size_t)ro * 256 + col] = sp.x;
                z1l[(size_t)ro * 256 + col] = sp.y;
            }
        }
    }
    // ---- phase 2: K=256, N=128 in two 64-col halves; A (z1) re-read from global (own rows) ----
    floatx4 acc2[8];
#pragma unroll
    for (int t = 0; t < 8; t++) acc2[t] = {0.f, 0.f, 0.f, 0.f};
    for (int hf = 0; hf < 2; hf++) {
        __syncthreads();
        {
            const float4* s1p = (const float4*)(B2h + hf * 16384);
            const float4* s2p = (const float4*)(B2l + hf * 16384);
            float4* d = (float4*)lds;
#pragma unroll
            for (int i = 0; i < 8; i++) {
                int t8 = threadIdx.x + 256 * i;                  // 0..2047
                int col = t8 >> 5, k8 = t8 & 31;
                int unit = col * 32 + (k8 ^ (col & 15));
                d[unit] = s1p[t8];
                d[2048 + unit] = s2p[t8];
            }
        }
        __syncthreads();
        if (valid) {
#pragma unroll
            for (int k0 = 0; k0 < 256; k0 += 32) {
                const int kb = k0 + quad * 8;
                const int kb8 = kb >> 3;
                short8 zh = *(const short8*)(z1h + (size_t)row * 256 + kb);
                short8 zl = *(const short8*)(z1l + (size_t)row * 256 + kb);
#pragma unroll
                for (int t = 0; t < 4; t++) {
                    int col = t * 16 + l15;
                    int unit = col * 32 + (kb8 ^ (col & 15));
                    const short* bp = lds + unit * 8;
                    short8 bh = *(const short8*)bp;
                    short8 bl = *(const short8*)(bp + 16384);
                    int ti = hf * 4 + t;
                    acc2[ti] = __builtin_amdgcn_mfma_f32_16x16x32_bf16(zh, bh, acc2[ti], 0, 0, 0);
                    acc2[ti] = __builtin_amdgcn_mfma_f32_16x16x32_bf16(zl, bh, acc2[ti], 0, 0, 0);
                    acc2[ti] = __builtin_amdgcn_mfma_f32_16x16x32_bf16(zh, bl, acc2[ti], 0, 0, 0);
                }
            }
        }
    }
    // ---- LN2 (wave-private, 128 cols) + outputs ----
    if (valid) {
#pragma unroll
        for (int t = 0; t < 8; t++) {
            int col = t * 16 + l15;
            float bv = b2[col];
#pragma unroll
            for (int r = 0; r < 4; r++) {
                acc2[t][r] += bv;
                if (HAS_RES) {
                    int ro = tile * 16 + quad * 4 + r;
                    acc2[t][r] += res[(size_t)ro * 128 + col];
                }
            }
        }
        float s1[4] = {0.f, 0.f, 0.f, 0.f}, s2[4] = {0.f, 0.f, 0.f, 0.f};
#pragma unroll
        for (int t = 0; t < 8; t++)
#pragma unroll
            for (int r = 0; r < 4; r++) { s1[r] += acc2[t][r]; s2[r] += acc2[t][r] * acc2[t][r]; }
#pragma unroll
        for (int m = 1; m <= 8; m <<= 1)
#pragma unroll
            for (int r = 0; r < 4; r++) {
                s1[r] += __shfl_xor(s1[r], m, 64);
                s2[r] += __shfl_xor(s2[r], m, 64);
            }
        float mean[4], rstd[4];
#pragma unroll
        for (int r = 0; r < 4; r++) {
            mean[r] = s1[r] * (1.f / 128.f);
            float var = s2[r] * (1.f / 128.f) - mean[r] * mean[r];
            rstd[r] = rsqrtf(var + 1e-5f);
        }
#pragma unroll
        for (int t = 0; t < 8; t++) {
            int col = t * 16 + l15;
            float gg = g2[col], bb = be2[col];
#pragma unroll
            for (int r = 0; r < 4; r++) {
                int ro = tile * 16 + quad * 4 + r;
                float x = acc2[t][r];
                float y = fmaxf((x - mean[r]) * rstd[r] * gg + bb, 0.f);
                if (FINAL) {
                    short2 sp = split_bf16(y);
                    Fh[(size_t)ro * 128 + col] = sp.x;
                    Fl[(size_t)ro * 128 + col] = sp.y;
                } else {
                    Hout[(size_t)ro * 128 + col] = x;
                    HinOut[(size_t)ro * 128 + col] = y;
                    int yb = (int)(unsigned short)f2bs(y);
                    int ob = __shfl_xor(yb, 1, 64);
                    if ((l15 & 1) == 0)
                        HP[(size_t)ro * 64 + t * 8 + (l15 >> 1)] =
                            (unsigned)yb | ((unsigned)ob << 16);
                }
            }
        }
    }
}

extern "C" void kernel_launch(void* const* d_in, const int* in_sizes, int n_in,
                              void* d_out, int out_size, void* d_ws, size_t ws_size,
                              hipStream_t stream)
{
    const float* x         = (const float*)d_in[0];
    const float* edge_attr = (const float*)d_in[1];
    const float* nw        = (const float*)d_in[2];
    const float* nb        = (const float*)d_in[3];
    const float* ew        = (const float*)d_in[4];
    const float* eb        = (const float*)d_in[5];
    const float* m1w       = (const float*)d_in[6];
    const float* m1b       = (const float*)d_in[7];
    const float* lng       = (const float*)d_in[8];
    const float* lnb       = (const float*)d_in[9];
    const float* m2w       = (const float*)d_in[10];
    const float* m2b       = (const float*)d_in[11];
    const float* tpr       = (const float*)d_in[12];
    const float* ng        = (const float*)d_in[13];
    const float* nbb       = (const float*)d_in[14];
    const float* lw        = (const float*)d_in[15];
    const float* lb        = (const float*)d_in[16];
    const int* ei  = (const int*)d_in[17];
    const int* src = ei;
    const int* dst = ei + NE;

    // ---- workspace carve (~230 MB) ----
    char* w = (char*)d_ws;
    unsigned* ea4 = (unsigned*)w; w += (size_t)NE * 128 * 2;                  // 122.88 MB
    int* src_csr  = (int*)w; w += (size_t)NE * 4;
    int* eidx_csr = (int*)w; w += (size_t)NE * 4;
    unsigned* hp  = (unsigned*)w; w += (size_t)NN * 64 * 4;                   // 7.68 MB packed bf16
    float* h   = (float*)w; w += (size_t)NN * 128 * 4;
    float* hin = (float*)w; w += (size_t)NN * 128 * 4;
    short* zbuf_h = (short*)w; w += (size_t)NN * 128 * 2;
    short* zbuf_l = (short*)w; w += (size_t)NN * 128 * 2;
    short* fin_h  = (short*)w; w += (size_t)NN * 128 * 2;
    short* fin_l  = (short*)w; w += (size_t)NN * 128 * 2;
    short* z1s_h  = (short*)w; w += (size_t)NN * 256 * 2;
    short* z1s_l  = (short*)w; w += (size_t)NN * 256 * 2;
    short* ew_h = (short*)w; w += (size_t)128 * 16 * 2;
    short* ew_l = (short*)w; w += (size_t)128 * 16 * 2;
    short* nw_h = (short*)w; w += (size_t)128 * 64 * 2;
    short* nw_l = (short*)w; w += (size_t)128 * 64 * 2;
    short* m1_h = (short*)w; w += (size_t)3 * 256 * 128 * 2;
    short* m1_l = (short*)w; w += (size_t)3 * 256 * 128 * 2;
    short* m2_h = (short*)w; w += (size_t)3 * 128 * 256 * 2;
    short* m2_l = (short*)w; w += (size_t)3 * 128 * 256 * 2;
    short* lw_h = (short*)w; w += (size_t)16 * 128 * 2;
    short* lw_l = (short*)w; w += (size_t)16 * 128 * 2;
    int* count  = (int*)w;   w += (size_t)NN * 4;
    int* cursor = (int*)w;   w += (size_t)NN * 4;
    int* rowptr = (int*)w;   w += (size_t)(NN + 1) * 4;

    // ---- CSR build ----
    zero_kernel<<<(2 * NN + 255) / 256, 256, 0, stream>>>(count, 2 * NN);
    hist_kernel<<<(NE + 255) / 256, 256, 0, stream>>>(dst, count);
    scan_kernel<<<1, 1024, 0, stream>>>(count, rowptr);
    scatter_kernel<<<(NE + 255) / 256, 256, 0, stream>>>(src, dst, rowptr, cursor,
                                                         src_csr, eidx_csr);

    // ---- weight pre-split ----
    presplit_all<<<(208896 + 255) / 256, 256, 0, stream>>>(
        ew, nw, m1w, m2w, lw, ew_h, ew_l, nw_h, nw_l, m1_h, m1_l, m2_h, m2_l, lw_h, lw_l);

    // ---- edge encoder (gathered, 4-edge-interleaved output) + node encoder ----
    gemm_ea<<<NE / 32, 256, 0, stream>>>(edge_attr, eidx_csr, ew_h, ew_l, eb, ea4);
    gemm_a32<64, 128><<<(NN / 16) * 8 / 4, 256, 0, stream>>>(x, nw_h, nw_l, nb, h, hp,
                                                             (NN / 16) * 8);

    const uint4* ea4q = (const uint4*)ea4;
    const int mgrid = (NROWT + 3) / 4;   // 469 blocks, 4 row-tiles each
    for (int layer = 0; layer < 3; ++layer) {
        const float* hi = (layer == 0) ? h : hin;   // residual source (fp32)
        agg_kernel<<<NN / 4, 256, 0, stream>>>(hp, hi, ea4q, src_csr, rowptr, tpr, layer,
                                               zbuf_h, zbuf_l);
        if (layer == 0) {
            mlp_fused<false, false><<<mgrid, 256, 0, stream>>>(
                zbuf_h, zbuf_l, m1_h, m1_l, m1b, lng, lnb,
                m2_h, m2_l, m2b, nullptr, ng + 128, nbb + 128,
                z1s_h, z1s_l, h, hin, hp, nullptr, nullptr);
        } else if (layer == 1) {
            mlp_fused<true, false><<<mgrid, 256, 0, stream>>>(
                zbuf_h, zbuf_l, m1_h + 32768, m1_l + 32768, m1b + 256, lng + 256, lnb + 256,
                m2_h + 32768, m2_l + 32768, m2b + 128, h, ng + 256, nbb + 256,
                z1s_h, z1s_l, h, hin, hp, nullptr, nullptr);
        } else {
            mlp_fused<true, true><<<mgrid, 256, 0, stream>>>(
                zbuf_h, zbuf_l, m1_h + 65536, m1_l + 65536, m1b + 512, lng + 512, lnb + 512,
                m2_h + 65536, m2_l + 65536, m2b + 256, h, ng, nbb,
                z1s_h, z1s_l, nullptr, nullptr, nullptr, fin_h, fin_l);
        }
    }
    // classifier
    gemm_s<128, 16, 1, 10><<<((NN / 16) + 3) / 4, 256, 0, stream>>>(
        fin_h, fin_l, lw_h, lw_l, lb, (float*)d_out, NN / 16);
}